// Round 2
// baseline (935.382 us; speedup 1.0000x reference)
//
#include <hip/hip_runtime.h>
#include <hip/hip_bf16.h>

// Problem: N=4,C=64,F=100,T=200,H=16 ; B=N*F=400, BT=80000
// Pipeline per b-chunk (NB rows): ln1 -> xg GEMM (fp32, bf16 out, gate-permuted)
//   -> LSTM recurrence -> attention (multiplicative causal mask BEFORE softmax,
//   handled exactly via suffix-V trick) -> combine+LN2+complex linear+LN3+PReLU+res.
// Chunk size NB picked at runtime from ws_size (largest of 400,200,100,50,25 that
// fits).  Per-chunk ws bytes = 8192 + NB*1,126,400:
//   bihh f32 [24][64]              @ 0        (8 KB reserved)
//   xr   f32 [NB][200][64]         @ 8192             (NB*51,200)
//   xi   f32 [NB][200][64]                            (NB*51,200)
//   xg   bf16 [24][200][NB][16][4]                    (NB*614,400) gate-permuted
//   h    f32 [24][NB][200][16]                        (NB*307,200)
//   att  f32 [8][NB][200][16]                         (NB*102,400)

static __device__ __forceinline__ float bf2f(unsigned short u) {
  return __uint_as_float(((unsigned)u) << 16);
}
static __device__ __forceinline__ float sigf(float x) {
  return __fdividef(1.f, 1.f + __expf(-x));
}
static __device__ __forceinline__ float tanh_(float x) {
  return 1.f - __fdividef(2.f, __expf(2.f * x) + 1.f);  // safe at +-inf
}

// ---------------- kernel A: LN1 over C, layout [N,C,F,T,2] -> xr/xi [bl][t][c]
__global__ __launch_bounds__(256) void k_ln1(const float* __restrict__ in,
    const float* __restrict__ w, const float* __restrict__ bsh,
    float* __restrict__ xr, float* __restrict__ xi, int b0) {
  __shared__ float is[64][101];   // [c][(tloc,ri)]
  __shared__ float os[100][65];   // [(tloc,ri)][c]
  int bid = blockIdx.x;
  int nfl = bid >> 2, tile = bid & 3;         // NB nf-local x 4 tiles of 50 t
  int nf = b0 + nfl;
  int t0 = tile * 50;
  int n = nf / 100, f = nf - n * 100;
  int tid = threadIdx.x;
  for (int i = 0; i < 7; ++i) {               // 64 rows x 25 float4
    int idx = tid + i * 256;
    if (idx < 1600) {
      int c = idx / 25, q = idx - c * 25;
      float4 v = *(const float4*)(in + (size_t)((n * 64 + c) * 100 + f) * 400
                                  + t0 * 2 + q * 4);
      is[c][q*4+0] = v.x; is[c][q*4+1] = v.y; is[c][q*4+2] = v.z; is[c][q*4+3] = v.w;
    }
  }
  __syncthreads();
  if (tid < 100) {
    float s = 0.f, ss = 0.f;
    #pragma unroll
    for (int c = 0; c < 64; ++c) { float v = is[c][tid]; s += v; ss += v * v; }
    float mean = s * 0.015625f;
    float var  = ss * 0.015625f - mean * mean;
    float rstd = rsqrtf(var + 1e-5f);
    #pragma unroll
    for (int c = 0; c < 64; ++c)
      os[tid][c] = (is[c][tid] - mean) * rstd * w[c] + bsh[c];
  }
  __syncthreads();
  for (int ri = 0; ri < 2; ++ri) {
    float* dst = ri ? xi : xr;
    for (int i = 0; i < 4; ++i) {             // 50 rows x 16 float4 per ri
      int idx = tid + i * 256;
      if (idx < 800) {
        int t = idx >> 4, q = idx & 15;
        float4 v;
        v.x = os[t*2+ri][q*4+0]; v.y = os[t*2+ri][q*4+1];
        v.z = os[t*2+ri][q*4+2]; v.w = os[t*2+ri][q*4+3];
        *(float4*)(dst + ((size_t)nfl * 200 + t0 + t) * 64 + q * 4) = v;
      }
    }
  }
}

// ---------------- tiny prep: bihh = bih + bhh
__global__ void k_prep(const float* __restrict__ a, const float* __restrict__ b,
                       float* __restrict__ o) {
  int i = blockIdx.x * 256 + threadIdx.x;
  if (i < 1536) o[i] = a[i] + b[i];
}

// ---------------- kernel B: xg = x_sel @ Wih[l]^T + bihh[l], bf16 out, permuted
// block: (l, mtile of 128).  thread: jq=tid&7 (8 j), mq=tid>>3 (4 m) -> 32 acc
// m = bl*200 + t  (bl local batch row), M = NB*200
__global__ __launch_bounds__(256) void k_xg(const float* __restrict__ xr,
    const float* __restrict__ xi, const float* __restrict__ Wih,
    const float* __restrict__ bihh, __hip_bfloat16* __restrict__ xg,
    int M, int NB) {
  __shared__ float xT[64][132];   // [c][m]
  __shared__ float wT[64][68];    // [c][j]
  int mtiles = (M + 127) >> 7;
  int bid = blockIdx.x;
  int l = bid / mtiles, mt = bid - l * mtiles;
  int m0 = mt * 128;
  int tid = threadIdx.x;
  int sel = (0xE54770 >> l) & 1;  // per-lstm real/imag selection
  const float* xs = sel ? xi : xr;
  for (int i = 0; i < 8; ++i) {   // x tile: 128 rows x 16 f4 (clamp OOB rows)
    int idx = tid + i * 256;
    int m = idx >> 4, c4 = idx & 15;
    int mg = m0 + m; if (mg >= M) mg = M - 1;
    float4 v = *(const float4*)(xs + (size_t)mg * 64 + c4 * 4);
    xT[c4*4+0][m] = v.x; xT[c4*4+1][m] = v.y; xT[c4*4+2][m] = v.z; xT[c4*4+3][m] = v.w;
  }
  for (int i = 0; i < 4; ++i) {   // w tile: 64 rows x 16 f4
    int idx = tid + i * 256;
    int j = idx >> 4, c4 = idx & 15;
    float4 v = *(const float4*)(Wih + (size_t)l * 4096 + j * 64 + c4 * 4);
    wT[c4*4+0][j] = v.x; wT[c4*4+1][j] = v.y; wT[c4*4+2][j] = v.z; wT[c4*4+3][j] = v.w;
  }
  __syncthreads();
  int jq = tid & 7, mq = tid >> 3;
  float4 a0[4], a1[4];
  #pragma unroll
  for (int mm = 0; mm < 4; ++mm) { a0[mm] = make_float4(0,0,0,0); a1[mm] = make_float4(0,0,0,0); }
  for (int c = 0; c < 64; ++c) {
    float4 xv = *(float4*)&xT[c][mq * 4];
    float4 w0 = *(float4*)&wT[c][jq * 8];
    float4 w1 = *(float4*)&wT[c][jq * 8 + 4];
    float xa[4] = {xv.x, xv.y, xv.z, xv.w};
    #pragma unroll
    for (int mm = 0; mm < 4; ++mm) {
      a0[mm].x += xa[mm]*w0.x; a0[mm].y += xa[mm]*w0.y;
      a0[mm].z += xa[mm]*w0.z; a0[mm].w += xa[mm]*w0.w;
      a1[mm].x += xa[mm]*w1.x; a1[mm].y += xa[mm]*w1.y;
      a1[mm].z += xa[mm]*w1.z; a1[mm].w += xa[mm]*w1.w;
    }
  }
  float bj[8];
  #pragma unroll
  for (int jj = 0; jj < 8; ++jj) bj[jj] = bihh[l * 64 + jq * 8 + jj];
  #pragma unroll
  for (int mm = 0; mm < 4; ++mm) {
    int m = m0 + mq * 4 + mm;         // m = bl*200 + t
    if (m >= M) continue;
    int bl = m / 200, t = m - bl * 200;
    size_t obase = ((size_t)(l * 200 + t) * NB + bl) * 64;
    float av[8] = {a0[mm].x, a0[mm].y, a0[mm].z, a0[mm].w,
                   a1[mm].x, a1[mm].y, a1[mm].z, a1[mm].w};
    #pragma unroll
    for (int jj = 0; jj < 8; ++jj) {
      int j = jq * 8 + jj;
      int k = j & 15, g = j >> 4;     // gate-permuted: [k][g]
      xg[obase + k * 4 + g] = __float2bfloat16(av[jj] + bj[jj]);
    }
  }
}

// ---------------- kernel R: LSTM recurrence. wave = 4 chains, lane=(bl,k).
// h shared via shfl within 16-lane groups; no barriers in t loop.
__global__ __launch_bounds__(256) void k_lstm(const __hip_bfloat16* __restrict__ xg,
    const float* __restrict__ Whh, float* __restrict__ hbuf, int NB) {
  int bgroups = (NB + 15) >> 4;
  int bid = blockIdx.x;                   // 24 l x bgroups
  int l = bid / bgroups, bg = bid - l * bgroups;
  int tid = threadIdx.x;
  int wave = tid >> 6, lane = tid & 63;
  int bl4 = lane >> 4, k = lane & 15;
  int b = bg * 16 + wave * 4 + bl4;       // local batch row
  bool live = b < NB;
  int bc = live ? b : NB - 1;
  float w[4][16];                         // Whh rows j=g*16+k, in registers
  #pragma unroll
  for (int g = 0; g < 4; ++g)
    #pragma unroll
    for (int q = 0; q < 4; ++q) {
      float4 v = *(const float4*)(Whh + (size_t)l * 1024 + (g * 16 + k) * 16 + q * 4);
      w[g][q*4+0] = v.x; w[g][q*4+1] = v.y; w[g][q*4+2] = v.z; w[g][q*4+3] = v.w;
    }
  float h = 0.f, c = 0.f;
  const ushort4* xgp = (const ushort4*)xg;          // one elem = 4 gates of (l,t,b,k)
  size_t tstride = (size_t)NB * 16;
  size_t idx0 = ((size_t)l * 200 * NB + bc) * 16 + k;
  size_t hbase = ((size_t)l * NB + bc) * 3200 + k;  // + t*16 per step
  ushort4 u = xgp[idx0];
  int grpbase = lane & 48;
  for (int t = 0; t < 200; ++t) {
    int tn = t < 199 ? t + 1 : 199;
    ushort4 unext = xgp[idx0 + (size_t)tn * tstride];   // prefetch
    float p0 = bf2f(u.x), p1 = bf2f(u.y), p2 = bf2f(u.z), p3 = bf2f(u.w);
    #pragma unroll
    for (int kk = 0; kk < 16; ++kk) {
      float hv = __shfl(h, grpbase | kk, 64);
      p0 += w[0][kk] * hv; p1 += w[1][kk] * hv;
      p2 += w[2][kk] * hv; p3 += w[3][kk] * hv;
    }
    float ig = sigf(p0), fg = sigf(p1), gg = tanh_(p2), og = sigf(p3);
    c = fg * c + ig * gg;
    h = og * tanh_(c);
    if (live) hbuf[hbase + t * 16] = h;
    u = unext;
  }
}

// ---------------- kernel C: attention per (branch, bl). Multiplicative causal
// mask before softmax: masked s get weight exp(0); handled via suffix-V init.
__global__ __launch_bounds__(256) void k_attn(const float* __restrict__ hbuf,
                                              float* __restrict__ att, int NB) {
  __shared__ float Q[200][17];
  __shared__ float K[200][16];
  __shared__ float V[200][16];
  __shared__ float Vs[200][17];
  int bid = blockIdx.x;                 // 8 br x NB
  int br = bid / NB, b = bid - br * NB;
  int tid = threadIdx.x;
  const float* qg = hbuf + ((size_t)(br * 3 + 0) * NB + b) * 3200;
  const float* kg = hbuf + ((size_t)(br * 3 + 1) * NB + b) * 3200;
  const float* vg = hbuf + ((size_t)(br * 3 + 2) * NB + b) * 3200;
  for (int i = 0; i < 4; ++i) {         // 200 rows x 4 f4 each of Q,K,V
    int idx = tid + i * 256;
    if (idx < 800) {
      int t = idx >> 2, q = idx & 3;
      float4 a = *(const float4*)(qg + t * 16 + q * 4);
      Q[t][q*4+0] = a.x; Q[t][q*4+1] = a.y; Q[t][q*4+2] = a.z; Q[t][q*4+3] = a.w;
      *(float4*)&K[t][q * 4] = *(const float4*)(kg + t * 16 + q * 4);
      *(float4*)&V[t][q * 4] = *(const float4*)(vg + t * 16 + q * 4);
    }
  }
  __syncthreads();
  if (tid < 16) {                       // suffix sums of V
    float acc = 0.f;
    Vs[199][tid] = 0.f;
    for (int t = 198; t >= 0; --t) { acc += V[t + 1][tid]; Vs[t][tid] = acc; }
  }
  __syncthreads();
  if (tid < 200) {
    int t = tid;
    float q0[16], va[16];
    #pragma unroll
    for (int k = 0; k < 16; ++k) q0[k] = Q[t][k] * 0.25f;   // fold /sqrt(16)
    #pragma unroll
    for (int k = 0; k < 16; ++k) va[k] = Vs[t][k];          // masked: weight exp(0)=1
    float S = (float)(199 - t);
    for (int s = 0; s <= t; ++s) {
      float e = 0.f;
      #pragma unroll
      for (int k = 0; k < 16; ++k) e += q0[k] * K[s][k];
      float wgt = __expf(e);
      S += wgt;
      #pragma unroll
      for (int k = 0; k < 16; ++k) va[k] += wgt * V[s][k];
    }
    float inv = __fdividef(1.f, S);
    float* dst = att + (((size_t)br * NB + b) * 200 + t) * 16;
    #pragma unroll
    for (int q = 0; q < 4; ++q) {
      float4 v; v.x = va[q*4+0]*inv; v.y = va[q*4+1]*inv;
      v.z = va[q*4+2]*inv; v.w = va[q*4+3]*inv;
      *(float4*)(dst + q * 4) = v;
    }
  }
}

// ---------------- kernel D: combine branches + LN2 + complex linear + LN3 +
// PReLU + residual, with LDS transpose for coalesced [N,C,F,T,2] IO.
__global__ __launch_bounds__(256) void k_out(const float* __restrict__ att,
    const float* __restrict__ in,
    const float* __restrict__ ln2w, const float* __restrict__ ln2b,
    const float* __restrict__ lrw, const float* __restrict__ lrb,
    const float* __restrict__ liw, const float* __restrict__ lib,
    const float* __restrict__ ln3w, const float* __restrict__ ln3b,
    const float* __restrict__ pa, float* __restrict__ out, int b0, int NB) {
  __shared__ float as_[8][40][17];
  __shared__ float ys[40][2][17];
  __shared__ float zs[64][81];
  int bid = blockIdx.x;                 // NB nf-local x 5 tiles of 40 t
  int nfl = bid / 5, tile = bid - nfl * 5;
  int nf = b0 + nfl;
  int t0 = tile * 40;
  int n = nf / 100, f = nf - n * 100;
  int tid = threadIdx.x;
  for (int i = 0; i < 5; ++i) {         // att: 8 br x 40 t x 4 f4
    int idx = tid + i * 256;
    int br = idx / 160, r = idx - br * 160;
    int t = r >> 2, q = r & 3;
    float4 v = *(const float4*)(att + (((size_t)br * NB + nfl) * 200 + t0 + t) * 16 + q * 4);
    as_[br][t][q*4+0] = v.x; as_[br][t][q*4+1] = v.y;
    as_[br][t][q*4+2] = v.z; as_[br][t][q*4+3] = v.w;
  }
  __syncthreads();
  if (tid < 80) {                       // combine + LN2 per (t,ri)
    int t = tid >> 1, ri = tid & 1;
    float vv[16]; float s = 0.f, ss = 0.f;
    #pragma unroll
    for (int k = 0; k < 16; ++k) {
      float v;
      if (ri == 0) v = as_[0][t][k] - as_[1][t][k] - as_[2][t][k] - as_[3][t][k];
      else         v = as_[4][t][k] + as_[5][t][k] + as_[6][t][k] - as_[7][t][k];
      vv[k] = v; s += v; ss += v * v;
    }
    float mean = s * 0.0625f;
    float var  = ss * 0.0625f - mean * mean;
    float rstd = rsqrtf(var + 1e-5f);
    #pragma unroll
    for (int k = 0; k < 16; ++k)
      ys[t][ri][k] = (vv[k] - mean) * rstd * ln2w[k] + ln2b[k];
  }
  __syncthreads();
  // complex linear 16->64 + LN3 over c (wave = 64 lanes = c) + PReLU
  int wv = tid >> 6, cc = tid & 63;
  float lr[16], li[16];
  #pragma unroll
  for (int q = 0; q < 4; ++q) {
    float4 v = *(const float4*)(lrw + cc * 16 + q * 4);
    lr[q*4+0] = v.x; lr[q*4+1] = v.y; lr[q*4+2] = v.z; lr[q*4+3] = v.w;
    float4 u = *(const float4*)(liw + cc * 16 + q * 4);
    li[q*4+0] = u.x; li[q*4+1] = u.y; li[q*4+2] = u.z; li[q*4+3] = u.w;
  }
  float brc = lrb[cc], bic = lib[cc];
  float w3 = ln3w[cc], b3 = ln3b[cc];
  float aP = pa[0];
  for (int tt = wv; tt < 40; tt += 4) {
    float zr = brc - bic, zi = brc + bic;
    #pragma unroll
    for (int k = 0; k < 16; ++k) {
      float yr = ys[tt][0][k], yi = ys[tt][1][k];
      zr += yr * lr[k] - yi * li[k];
      zi += yi * lr[k] + yr * li[k];
    }
    float s1 = zr, s2 = zr * zr, s3 = zi, s4 = zi * zi;
    #pragma unroll
    for (int m = 1; m < 64; m <<= 1) {
      s1 += __shfl_xor(s1, m, 64);
      s2 += __shfl_xor(s2, m, 64);
      s3 += __shfl_xor(s3, m, 64);
      s4 += __shfl_xor(s4, m, 64);
    }
    float mr = s1 * 0.015625f, vr = s2 * 0.015625f - mr * mr;
    float mi = s3 * 0.015625f, vi = s4 * 0.015625f - mi * mi;
    float r1 = (zr - mr) * rsqrtf(vr + 1e-5f) * w3 + b3;
    float r2 = (zi - mi) * rsqrtf(vi + 1e-5f) * w3 + b3;
    r1 = r1 >= 0.f ? r1 : aP * r1;
    r2 = r2 >= 0.f ? r2 : aP * r2;
    zs[cc][tt * 2 + 0] = r1;
    zs[cc][tt * 2 + 1] = r2;
  }
  __syncthreads();
  for (int i = 0; i < 5; ++i) {         // residual + coalesced write
    int idx = tid + i * 256;            // 64 c x 20 f4
    int c = idx / 20, q = idx - c * 20;
    size_t gaddr = (size_t)((n * 64 + c) * 100 + f) * 400 + t0 * 2 + q * 4;
    float4 v = *(const float4*)(in + gaddr);
    float4 z;
    z.x = zs[c][q*4+0] + v.x; z.y = zs[c][q*4+1] + v.y;
    z.z = zs[c][q*4+2] + v.z; z.w = zs[c][q*4+3] + v.w;
    *(float4*)(out + gaddr) = z;
  }
}

extern "C" void kernel_launch(void* const* d_in, const int* in_sizes, int n_in,
                              void* d_out, int out_size, void* d_ws, size_t ws_size,
                              hipStream_t stream) {
  (void)in_sizes; (void)n_in; (void)out_size;
  const float* inputs = (const float*)d_in[0];
  const float* Wih  = (const float*)d_in[1];
  const float* Whh  = (const float*)d_in[2];
  const float* bih  = (const float*)d_in[3];
  const float* bhh  = (const float*)d_in[4];
  const float* ln1w = (const float*)d_in[5];
  const float* ln1b = (const float*)d_in[6];
  const float* ln2w = (const float*)d_in[7];
  const float* ln2b = (const float*)d_in[8];
  const float* lrw  = (const float*)d_in[9];
  const float* lrb  = (const float*)d_in[10];
  const float* liw  = (const float*)d_in[11];
  const float* lib  = (const float*)d_in[12];
  const float* ln3w = (const float*)d_in[13];
  const float* ln3b = (const float*)d_in[14];
  const float* pa   = (const float*)d_in[15];
  float* out = (float*)d_out;
  char* ws = (char*)d_ws;

  // pick largest chunk NB (in 400,200,100,50,25) whose buffers fit ws_size
  int NB = 400;
  while (NB > 25 && (size_t)NB * 1126400ull + 8192ull > ws_size) NB /= 2;
  int nch = 400 / NB;

  float* bihh = (float*)(ws + 0);                       // 1536 f32, 8 KB slot
  size_t o_xr = 8192;
  size_t o_xi = o_xr + (size_t)NB * 51200;
  size_t o_xg = o_xi + (size_t)NB * 51200;
  size_t o_h  = o_xg + (size_t)NB * 614400;
  size_t o_at = o_h  + (size_t)NB * 307200;
  float* xr   = (float*)(ws + o_xr);
  float* xi   = (float*)(ws + o_xi);
  __hip_bfloat16* xg = (__hip_bfloat16*)(ws + o_xg);
  float* hbuf = (float*)(ws + o_h);
  float* att  = (float*)(ws + o_at);

  k_prep<<<6, 256, 0, stream>>>(bih, bhh, bihh);
  int M = NB * 200;
  int mtiles = (M + 127) >> 7;
  int bgroups = (NB + 15) >> 4;
  for (int ch = 0; ch < nch; ++ch) {
    int b0 = ch * NB;
    k_ln1 <<<NB * 4,        256, 0, stream>>>(inputs, ln1w, ln1b, xr, xi, b0);
    k_xg  <<<24 * mtiles,   256, 0, stream>>>(xr, xi, Wih, bihh, xg, M, NB);
    k_lstm<<<24 * bgroups,  256, 0, stream>>>(xg, Whh, hbuf, NB);
    k_attn<<<8 * NB,        256, 0, stream>>>(hbuf, att, NB);
    k_out <<<NB * 5,        256, 0, stream>>>(att, inputs, ln2w, ln2b, lrw, lrb,
                                              liw, lib, ln3w, ln3b, pa, out, b0, NB);
  }
}

// Round 4
// 918.290 us; speedup vs baseline: 1.0186x; 1.0186x over previous
//
#include <hip/hip_runtime.h>
#include <hip/hip_bf16.h>

// Problem: N=4,C=64,F=100,T=200,H=16 ; B=N*F=400, BT=80000
// Pipeline per b-chunk (NB rows): ln1 -> xg GEMM (fp32, bf16 out, gate-permuted)
//   -> LSTM recurrence (1 wave/chain, readlane matvec) -> attention
//   (multiplicative causal mask BEFORE softmax, suffix-V trick)
//   -> combine+LN2+complex linear+LN3+PReLU+residual.
// Chunk size NB picked at runtime from ws_size.
// Per-chunk ws bytes = 8192 + NB*1,126,400.

static __device__ __forceinline__ float bf2f(unsigned short u) {
  return __uint_as_float(((unsigned)u) << 16);
}
static __device__ __forceinline__ float rdlane(float v, int lane) {
  return __uint_as_float(__builtin_amdgcn_readlane(__float_as_uint(v), lane));
}

// ---------------- kernel A: LN1 over C, layout [N,C,F,T,2] -> xr/xi [bl][t][c]
__global__ __launch_bounds__(256) void k_ln1(const float* __restrict__ in,
    const float* __restrict__ w, const float* __restrict__ bsh,
    float* __restrict__ xr, float* __restrict__ xi, int b0) {
  __shared__ float is[64][101];   // [c][(tloc,ri)]
  __shared__ float os[100][65];   // [(tloc,ri)][c]
  int bid = blockIdx.x;
  int nfl = bid >> 2, tile = bid & 3;         // NB nf-local x 4 tiles of 50 t
  int nf = b0 + nfl;
  int t0 = tile * 50;
  int n = nf / 100, f = nf - n * 100;
  int tid = threadIdx.x;
  for (int i = 0; i < 7; ++i) {               // 64 rows x 25 float4
    int idx = tid + i * 256;
    if (idx < 1600) {
      int c = idx / 25, q = idx - c * 25;
      float4 v = *(const float4*)(in + (size_t)((n * 64 + c) * 100 + f) * 400
                                  + t0 * 2 + q * 4);
      is[c][q*4+0] = v.x; is[c][q*4+1] = v.y; is[c][q*4+2] = v.z; is[c][q*4+3] = v.w;
    }
  }
  __syncthreads();
  if (tid < 100) {
    float s = 0.f, ss = 0.f;
    #pragma unroll
    for (int c = 0; c < 64; ++c) { float v = is[c][tid]; s += v; ss += v * v; }
    float mean = s * 0.015625f;
    float var  = ss * 0.015625f - mean * mean;
    float rstd = rsqrtf(var + 1e-5f);
    #pragma unroll
    for (int c = 0; c < 64; ++c)
      os[tid][c] = (is[c][tid] - mean) * rstd * w[c] + bsh[c];
  }
  __syncthreads();
  for (int ri = 0; ri < 2; ++ri) {
    float* dst = ri ? xi : xr;
    for (int i = 0; i < 4; ++i) {             // 50 rows x 16 float4 per ri
      int idx = tid + i * 256;
      if (idx < 800) {
        int t = idx >> 4, q = idx & 15;
        float4 v;
        v.x = os[t*2+ri][q*4+0]; v.y = os[t*2+ri][q*4+1];
        v.z = os[t*2+ri][q*4+2]; v.w = os[t*2+ri][q*4+3];
        *(float4*)(dst + ((size_t)nfl * 200 + t0 + t) * 64 + q * 4) = v;
      }
    }
  }
}

// ---------------- tiny prep: bihh = bih + bhh
__global__ void k_prep(const float* __restrict__ a, const float* __restrict__ b,
                       float* __restrict__ o) {
  int i = blockIdx.x * 256 + threadIdx.x;
  if (i < 1536) o[i] = a[i] + b[i];
}

// ---------------- kernel B: xg = x_sel @ Wih[l]^T + bihh[l], bf16 out, permuted
__global__ __launch_bounds__(256) void k_xg(const float* __restrict__ xr,
    const float* __restrict__ xi, const float* __restrict__ Wih,
    const float* __restrict__ bihh, __hip_bfloat16* __restrict__ xg,
    int M, int NB) {
  __shared__ float xT[64][132];   // [c][m]
  __shared__ float wT[64][68];    // [c][j]
  int mtiles = (M + 127) >> 7;
  int bid = blockIdx.x;
  int l = bid / mtiles, mt = bid - l * mtiles;
  int m0 = mt * 128;
  int tid = threadIdx.x;
  int sel = (0xE54770 >> l) & 1;  // per-lstm real/imag selection
  const float* xs = sel ? xi : xr;
  for (int i = 0; i < 8; ++i) {   // x tile: 128 rows x 16 f4 (clamp OOB rows)
    int idx = tid + i * 256;
    int m = idx >> 4, c4 = idx & 15;
    int mg = m0 + m; if (mg >= M) mg = M - 1;
    float4 v = *(const float4*)(xs + (size_t)mg * 64 + c4 * 4);
    xT[c4*4+0][m] = v.x; xT[c4*4+1][m] = v.y; xT[c4*4+2][m] = v.z; xT[c4*4+3][m] = v.w;
  }
  for (int i = 0; i < 4; ++i) {   // w tile: 64 rows x 16 f4
    int idx = tid + i * 256;
    int j = idx >> 4, c4 = idx & 15;
    float4 v = *(const float4*)(Wih + (size_t)l * 4096 + j * 64 + c4 * 4);
    wT[c4*4+0][j] = v.x; wT[c4*4+1][j] = v.y; wT[c4*4+2][j] = v.z; wT[c4*4+3][j] = v.w;
  }
  __syncthreads();
  int jq = tid & 7, mq = tid >> 3;
  float4 a0[4], a1[4];
  #pragma unroll
  for (int mm = 0; mm < 4; ++mm) { a0[mm] = make_float4(0,0,0,0); a1[mm] = make_float4(0,0,0,0); }
  for (int c = 0; c < 64; ++c) {
    float4 xv = *(float4*)&xT[c][mq * 4];
    float4 w0 = *(float4*)&wT[c][jq * 8];
    float4 w1 = *(float4*)&wT[c][jq * 8 + 4];
    float xa[4] = {xv.x, xv.y, xv.z, xv.w};
    #pragma unroll
    for (int mm = 0; mm < 4; ++mm) {
      a0[mm].x += xa[mm]*w0.x; a0[mm].y += xa[mm]*w0.y;
      a0[mm].z += xa[mm]*w0.z; a0[mm].w += xa[mm]*w0.w;
      a1[mm].x += xa[mm]*w1.x; a1[mm].y += xa[mm]*w1.y;
      a1[mm].z += xa[mm]*w1.z; a1[mm].w += xa[mm]*w1.w;
    }
  }
  float bj[8];
  #pragma unroll
  for (int jj = 0; jj < 8; ++jj) bj[jj] = bihh[l * 64 + jq * 8 + jj];
  #pragma unroll
  for (int mm = 0; mm < 4; ++mm) {
    int m = m0 + mq * 4 + mm;         // m = bl*200 + t
    if (m >= M) continue;
    int bl = m / 200, t = m - bl * 200;
    size_t obase = ((size_t)(l * 200 + t) * NB + bl) * 64;
    float av[8] = {a0[mm].x, a0[mm].y, a0[mm].z, a0[mm].w,
                   a1[mm].x, a1[mm].y, a1[mm].z, a1[mm].w};
    #pragma unroll
    for (int jj = 0; jj < 8; ++jj) {
      int j = jq * 8 + jj;
      int k = j & 15, g = j >> 4;     // gate-permuted: [k][g]
      xg[obase + k * 4 + g] = __float2bfloat16(av[jj] + bj[jj]);
    }
  }
}

// ---------------- kernel R: LSTM recurrence, one wave per chain.
// lane j = gate j (g=j>>4 in {i,f,g,o}, k=j&15). h[k] replicated in all 4
// 16-lane rows, so h[k] lives in physical lane k (row 0): the matvec uses
// v_readlane (h is wave-uniform data) -> 16 FMAs with SGPR operand; only 4
// __shfl per step gather the i,f,g,o activations. No DPP, no probes.
__global__ __launch_bounds__(256) void k_lstm(const __hip_bfloat16* __restrict__ xg,
    const float* __restrict__ Whh, float* __restrict__ hbuf, int NB) {
  int tid = threadIdx.x;
  int wave = tid >> 6, j = tid & 63;
  int chain = blockIdx.x * 4 + wave;      // 24*NB chains, NB*6 blocks
  int l = chain / NB, b = chain - l * NB;
  int g = j >> 4, k = j & 15;
  const float* wrow = Whh + (size_t)l * 1024 + j * 16;   // W[j][0..15]
  float4 w0 = ((const float4*)wrow)[0];
  float4 w1 = ((const float4*)wrow)[1];
  float4 w2 = ((const float4*)wrow)[2];
  float4 w3 = ((const float4*)wrow)[3];
  int s_i = k, s_f = 16 + k, s_g = 32 + k, s_o = 48 + k;
  bool isg = (g == 2);
  bool row0 = (j < 16);
  const unsigned short* xgp = (const unsigned short*)xg;
  size_t tstride = (size_t)NB * 64;
  size_t idx0 = ((size_t)l * 200 * NB + b) * 64 + k * 4 + g;  // [k][g] layout
  float* hptr = hbuf + ((size_t)l * NB + b) * 3200 + k;
  float h = 0.f, c = 0.f;
  unsigned short u = xgp[idx0];
  for (int t = 0; t < 200; ++t) {
    int tn = t < 199 ? t + 1 : 199;
    unsigned short unext = xgp[idx0 + (size_t)tn * tstride];  // prefetch
    float p = bf2f(u);
    // p += W[j] . h ; h[r] is in lane r (wave-uniform) -> readlane to SGPR
    p += w0.x * rdlane(h, 0);  p += w0.y * rdlane(h, 1);
    p += w0.z * rdlane(h, 2);  p += w0.w * rdlane(h, 3);
    p += w1.x * rdlane(h, 4);  p += w1.y * rdlane(h, 5);
    p += w1.z * rdlane(h, 6);  p += w1.w * rdlane(h, 7);
    p += w2.x * rdlane(h, 8);  p += w2.y * rdlane(h, 9);
    p += w2.z * rdlane(h, 10); p += w2.w * rdlane(h, 11);
    p += w3.x * rdlane(h, 12); p += w3.y * rdlane(h, 13);
    p += w3.z * rdlane(h, 14); p += w3.w * rdlane(h, 15);
    // one activation per lane: sigmoid, or tanh = 2*sigmoid(2x)-1 for g-gate
    float xs2 = isg ? (p + p) : p;
    float s = __fdividef(1.f, 1.f + __expf(-xs2));
    float av = isg ? (s + s - 1.f) : s;
    // gather the 4 gate activations for this lane's k
    float iv = __shfl(av, s_i, 64);
    float fv = __shfl(av, s_f, 64);
    float gv = __shfl(av, s_g, 64);
    float ov = __shfl(av, s_o, 64);
    c = fv * c + iv * gv;
    float s2 = __fdividef(1.f, 1.f + __expf(-2.f * c));
    h = ov * (s2 + s2 - 1.f);               // tanh(c), replicated per k
    if (row0) hptr[t * 16] = h;
    u = unext;
  }
}

// ---------------- kernel C: attention per (branch, bl). Multiplicative causal
// mask before softmax: masked s get weight exp(0); handled via suffix-V init.
__global__ __launch_bounds__(256) void k_attn(const float* __restrict__ hbuf,
                                              float* __restrict__ att, int NB) {
  __shared__ float Q[200][17];
  __shared__ float K[200][16];
  __shared__ float V[200][16];
  __shared__ float Vs[200][17];
  int bid = blockIdx.x;                 // 8 br x NB
  int br = bid / NB, b = bid - br * NB;
  int tid = threadIdx.x;
  const float* qg = hbuf + ((size_t)(br * 3 + 0) * NB + b) * 3200;
  const float* kg = hbuf + ((size_t)(br * 3 + 1) * NB + b) * 3200;
  const float* vg = hbuf + ((size_t)(br * 3 + 2) * NB + b) * 3200;
  for (int i = 0; i < 4; ++i) {         // 200 rows x 4 f4 each of Q,K,V
    int idx = tid + i * 256;
    if (idx < 800) {
      int t = idx >> 2, q = idx & 3;
      float4 a = *(const float4*)(qg + t * 16 + q * 4);
      Q[t][q*4+0] = a.x; Q[t][q*4+1] = a.y; Q[t][q*4+2] = a.z; Q[t][q*4+3] = a.w;
      *(float4*)&K[t][q * 4] = *(const float4*)(kg + t * 16 + q * 4);
      *(float4*)&V[t][q * 4] = *(const float4*)(vg + t * 16 + q * 4);
    }
  }
  __syncthreads();
  if (tid < 16) {                       // suffix sums of V
    float acc = 0.f;
    Vs[199][tid] = 0.f;
    for (int t = 198; t >= 0; --t) { acc += V[t + 1][tid]; Vs[t][tid] = acc; }
  }
  __syncthreads();
  if (tid < 200) {
    int t = tid;
    float q0[16], va[16];
    #pragma unroll
    for (int k = 0; k < 16; ++k) q0[k] = Q[t][k] * 0.25f;   // fold /sqrt(16)
    #pragma unroll
    for (int k = 0; k < 16; ++k) va[k] = Vs[t][k];          // masked: weight exp(0)=1
    float S = (float)(199 - t);
    for (int s = 0; s <= t; ++s) {
      float e = 0.f;
      #pragma unroll
      for (int k = 0; k < 16; ++k) e += q0[k] * K[s][k];
      float wgt = __expf(e);
      S += wgt;
      #pragma unroll
      for (int k = 0; k < 16; ++k) va[k] += wgt * V[s][k];
    }
    float inv = __fdividef(1.f, S);
    float* dst = att + (((size_t)br * NB + b) * 200 + t) * 16;
    #pragma unroll
    for (int q = 0; q < 4; ++q) {
      float4 v; v.x = va[q*4+0]*inv; v.y = va[q*4+1]*inv;
      v.z = va[q*4+2]*inv; v.w = va[q*4+3]*inv;
      *(float4*)(dst + q * 4) = v;
    }
  }
}

// ---------------- kernel D: combine branches + LN2 + complex linear + LN3 +
// PReLU + residual, with LDS transpose for coalesced [N,C,F,T,2] IO.
__global__ __launch_bounds__(256) void k_out(const float* __restrict__ att,
    const float* __restrict__ in,
    const float* __restrict__ ln2w, const float* __restrict__ ln2b,
    const float* __restrict__ lrw, const float* __restrict__ lrb,
    const float* __restrict__ liw, const float* __restrict__ lib,
    const float* __restrict__ ln3w, const float* __restrict__ ln3b,
    const float* __restrict__ pa, float* __restrict__ out, int b0, int NB) {
  __shared__ float as_[8][40][17];
  __shared__ float ys[40][2][17];
  __shared__ float zs[64][81];
  int bid = blockIdx.x;                 // NB nf-local x 5 tiles of 40 t
  int nfl = bid / 5, tile = bid - nfl * 5;
  int nf = b0 + nfl;
  int t0 = tile * 40;
  int n = nf / 100, f = nf - n * 100;
  int tid = threadIdx.x;
  for (int i = 0; i < 5; ++i) {         // att: 8 br x 40 t x 4 f4
    int idx = tid + i * 256;
    int br = idx / 160, r = idx - br * 160;
    int t = r >> 2, q = r & 3;
    float4 v = *(const float4*)(att + (((size_t)br * NB + nfl) * 200 + t0 + t) * 16 + q * 4);
    as_[br][t][q*4+0] = v.x; as_[br][t][q*4+1] = v.y;
    as_[br][t][q*4+2] = v.z; as_[br][t][q*4+3] = v.w;
  }
  __syncthreads();
  if (tid < 80) {                       // combine + LN2 per (t,ri)
    int t = tid >> 1, ri = tid & 1;
    float vv[16]; float s = 0.f, ss = 0.f;
    #pragma unroll
    for (int k = 0; k < 16; ++k) {
      float v;
      if (ri == 0) v = as_[0][t][k] - as_[1][t][k] - as_[2][t][k] - as_[3][t][k];
      else         v = as_[4][t][k] + as_[5][t][k] + as_[6][t][k] - as_[7][t][k];
      vv[k] = v; s += v; ss += v * v;
    }
    float mean = s * 0.0625f;
    float var  = ss * 0.0625f - mean * mean;
    float rstd = rsqrtf(var + 1e-5f);
    #pragma unroll
    for (int k = 0; k < 16; ++k)
      ys[t][ri][k] = (vv[k] - mean) * rstd * ln2w[k] + ln2b[k];
  }
  __syncthreads();
  // complex linear 16->64 + LN3 over c (wave = 64 lanes = c) + PReLU
  int wv = tid >> 6, cc = tid & 63;
  float lr[16], li[16];
  #pragma unroll
  for (int q = 0; q < 4; ++q) {
    float4 v = *(const float4*)(lrw + cc * 16 + q * 4);
    lr[q*4+0] = v.x; lr[q*4+1] = v.y; lr[q*4+2] = v.z; lr[q*4+3] = v.w;
    float4 u = *(const float4*)(liw + cc * 16 + q * 4);
    li[q*4+0] = u.x; li[q*4+1] = u.y; li[q*4+2] = u.z; li[q*4+3] = u.w;
  }
  float brc = lrb[cc], bic = lib[cc];
  float w3 = ln3w[cc], b3 = ln3b[cc];
  float aP = pa[0];
  for (int tt = wv; tt < 40; tt += 4) {
    float zr = brc - bic, zi = brc + bic;
    #pragma unroll
    for (int k = 0; k < 16; ++k) {
      float yr = ys[tt][0][k], yi = ys[tt][1][k];
      zr += yr * lr[k] - yi * li[k];
      zi += yi * lr[k] + yr * li[k];
    }
    float s1 = zr, s2 = zr * zr, s3 = zi, s4 = zi * zi;
    #pragma unroll
    for (int m = 1; m < 64; m <<= 1) {
      s1 += __shfl_xor(s1, m, 64);
      s2 += __shfl_xor(s2, m, 64);
      s3 += __shfl_xor(s3, m, 64);
      s4 += __shfl_xor(s4, m, 64);
    }
    float mr = s1 * 0.015625f, vr = s2 * 0.015625f - mr * mr;
    float mi = s3 * 0.015625f, vi = s4 * 0.015625f - mi * mi;
    float r1 = (zr - mr) * rsqrtf(vr + 1e-5f) * w3 + b3;
    float r2 = (zi - mi) * rsqrtf(vi + 1e-5f) * w3 + b3;
    r1 = r1 >= 0.f ? r1 : aP * r1;
    r2 = r2 >= 0.f ? r2 : aP * r2;
    zs[cc][tt * 2 + 0] = r1;
    zs[cc][tt * 2 + 1] = r2;
  }
  __syncthreads();
  for (int i = 0; i < 5; ++i) {         // residual + coalesced write
    int idx = tid + i * 256;            // 64 c x 20 f4
    int c = idx / 20, q = idx - c * 20;
    size_t gaddr = (size_t)((n * 64 + c) * 100 + f) * 400 + t0 * 2 + q * 4;
    float4 v = *(const float4*)(in + gaddr);
    float4 z;
    z.x = zs[c][q*4+0] + v.x; z.y = zs[c][q*4+1] + v.y;
    z.z = zs[c][q*4+2] + v.z; z.w = zs[c][q*4+3] + v.w;
    *(float4*)(out + gaddr) = z;
  }
}

extern "C" void kernel_launch(void* const* d_in, const int* in_sizes, int n_in,
                              void* d_out, int out_size, void* d_ws, size_t ws_size,
                              hipStream_t stream) {
  (void)in_sizes; (void)n_in; (void)out_size;
  const float* inputs = (const float*)d_in[0];
  const float* Wih  = (const float*)d_in[1];
  const float* Whh  = (const float*)d_in[2];
  const float* bih  = (const float*)d_in[3];
  const float* bhh  = (const float*)d_in[4];
  const float* ln1w = (const float*)d_in[5];
  const float* ln1b = (const float*)d_in[6];
  const float* ln2w = (const float*)d_in[7];
  const float* ln2b = (const float*)d_in[8];
  const float* lrw  = (const float*)d_in[9];
  const float* lrb  = (const float*)d_in[10];
  const float* liw  = (const float*)d_in[11];
  const float* lib  = (const float*)d_in[12];
  const float* ln3w = (const float*)d_in[13];
  const float* ln3b = (const float*)d_in[14];
  const float* pa   = (const float*)d_in[15];
  float* out = (float*)d_out;
  char* ws = (char*)d_ws;

  // pick largest chunk NB (in 400,200,100,50,25) whose buffers fit ws_size
  int NB = 400;
  while (NB > 25 && (size_t)NB * 1126400ull + 8192ull > ws_size) NB /= 2;
  int nch = 400 / NB;

  float* bihh = (float*)(ws + 0);                       // 1536 f32, 8 KB slot
  size_t o_xr = 8192;
  size_t o_xi = o_xr + (size_t)NB * 51200;
  size_t o_xg = o_xi + (size_t)NB * 51200;
  size_t o_h  = o_xg + (size_t)NB * 614400;
  size_t o_at = o_h  + (size_t)NB * 307200;
  float* xr   = (float*)(ws + o_xr);
  float* xi   = (float*)(ws + o_xi);
  __hip_bfloat16* xg = (__hip_bfloat16*)(ws + o_xg);
  float* hbuf = (float*)(ws + o_h);
  float* att  = (float*)(ws + o_at);

  k_prep<<<6, 256, 0, stream>>>(bih, bhh, bihh);
  int M = NB * 200;
  int mtiles = (M + 127) >> 7;
  for (int ch = 0; ch < nch; ++ch) {
    int b0 = ch * NB;
    k_ln1 <<<NB * 4,      256, 0, stream>>>(inputs, ln1w, ln1b, xr, xi, b0);
    k_xg  <<<24 * mtiles, 256, 0, stream>>>(xr, xi, Wih, bihh, xg, M, NB);
    k_lstm<<<NB * 6,      256, 0, stream>>>(xg, Whh, hbuf, NB);   // 24*NB waves
    k_attn<<<8 * NB,      256, 0, stream>>>(hbuf, att, NB);
    k_out <<<NB * 5,      256, 0, stream>>>(att, inputs, ln2w, ln2b, lrw, lrb,
                                            liw, lib, ln3w, ln3b, pa, out, b0, NB);
  }
}

// Round 5
// 894.669 us; speedup vs baseline: 1.0455x; 1.0264x over previous
//
#include <hip/hip_runtime.h>
#include <hip/hip_bf16.h>

// Problem: N=4,C=64,F=100,T=200,H=16 ; B=N*F=400, BT=80000
// Pipeline per b-chunk (NB rows): ln1 (fp32->bf16 x) -> xg GEMM (MFMA bf16,
//   bf16 out, gate-permuted) -> LSTM recurrence (1 wave/chain, readlane matvec
//   tree + xor-butterfly gate exchange) -> attention (multiplicative causal
//   mask BEFORE softmax, suffix-V trick) -> combine+LN2+complex linear+LN3+
//   PReLU+residual.
// ws: header 204800 B (bihh fp32 @0, Wih-bf16 @8192), then per chunk:
//   xr bf16 [NB][200][64] (NB*25600), xi same, xg bf16 [24][200][NB][16][4]
//   (NB*614400), h f32 [24][NB][200][16] (NB*307200), att f32 (NB*102400).
// Total = 204800 + NB*1,075,200.

typedef __attribute__((ext_vector_type(8))) short bf16x8;
typedef __attribute__((ext_vector_type(4))) float f32x4;

static __device__ __forceinline__ float bf2f(unsigned short u) {
  return __uint_as_float(((unsigned)u) << 16);
}
static __device__ __forceinline__ unsigned short f2bfu(float x) {
  __hip_bfloat16 h = __float2bfloat16(x);
  return *(unsigned short*)&h;
}
static __device__ __forceinline__ float rdlane(float v, int lane) {
  return __uint_as_float(__builtin_amdgcn_readlane(__float_as_uint(v), lane));
}

// ---------------- kernel A: LN1 over C -> xr/xi bf16 [bl][t][c]
__global__ __launch_bounds__(256) void k_ln1(const float* __restrict__ in,
    const float* __restrict__ w, const float* __restrict__ bsh,
    unsigned short* __restrict__ xr, unsigned short* __restrict__ xi, int b0) {
  __shared__ float is[64][101];   // [c][(tloc,ri)]
  __shared__ float os[100][65];   // [(tloc,ri)][c]
  int bid = blockIdx.x;
  int nfl = bid >> 2, tile = bid & 3;         // NB nf-local x 4 tiles of 50 t
  int nf = b0 + nfl;
  int t0 = tile * 50;
  int n = nf / 100, f = nf - n * 100;
  int tid = threadIdx.x;
  for (int i = 0; i < 7; ++i) {               // 64 rows x 25 float4
    int idx = tid + i * 256;
    if (idx < 1600) {
      int c = idx / 25, q = idx - c * 25;
      float4 v = *(const float4*)(in + (size_t)((n * 64 + c) * 100 + f) * 400
                                  + t0 * 2 + q * 4);
      is[c][q*4+0] = v.x; is[c][q*4+1] = v.y; is[c][q*4+2] = v.z; is[c][q*4+3] = v.w;
    }
  }
  __syncthreads();
  if (tid < 100) {
    float s = 0.f, ss = 0.f;
    #pragma unroll
    for (int c = 0; c < 64; ++c) { float v = is[c][tid]; s += v; ss += v * v; }
    float mean = s * 0.015625f;
    float var  = ss * 0.015625f - mean * mean;
    float rstd = rsqrtf(var + 1e-5f);
    #pragma unroll
    for (int c = 0; c < 64; ++c)
      os[tid][c] = (is[c][tid] - mean) * rstd * w[c] + bsh[c];
  }
  __syncthreads();
  for (int ri = 0; ri < 2; ++ri) {
    unsigned short* dst = ri ? xi : xr;
    for (int i = 0; i < 4; ++i) {             // 50 rows x 16 ushort4 per ri
      int idx = tid + i * 256;
      if (idx < 800) {
        int t = idx >> 4, q = idx & 15;
        ushort4 v;
        v.x = f2bfu(os[t*2+ri][q*4+0]); v.y = f2bfu(os[t*2+ri][q*4+1]);
        v.z = f2bfu(os[t*2+ri][q*4+2]); v.w = f2bfu(os[t*2+ri][q*4+3]);
        *(ushort4*)(dst + ((size_t)nfl * 200 + t0 + t) * 64 + q * 4) = v;
      }
    }
  }
}

// ---------------- prep: bihh = bih + bhh ; wbf = bf16(Wih)
__global__ void k_prep(const float* __restrict__ bih, const float* __restrict__ bhh,
                       const float* __restrict__ Wih, float* __restrict__ bihh,
                       unsigned short* __restrict__ wbf) {
  int i = blockIdx.x * 256 + threadIdx.x;
  if (i < 1536) bihh[i] = bih[i] + bhh[i];
  if (i < 98304) wbf[i] = f2bfu(Wih[i]);
}

// ---------------- kernel B: xg = x_sel @ Wih[l]^T + bihh[l] via MFMA bf16.
// One wave = 16-row m-strip x all 64 j. A-frag: m=lane&15, k=quad*8+e (m120-
// verified). B-frag dual: n=lane&15, k=quad*8+e. D: col=lane&15, row=quad*4+r.
// No LDS, no barriers; early-exit safe.
__global__ __launch_bounds__(256) void k_xg(const unsigned short* __restrict__ xr,
    const unsigned short* __restrict__ xi, const unsigned short* __restrict__ wbf,
    const float* __restrict__ bihh, __hip_bfloat16* __restrict__ xg,
    int M, int NB, int nsb) {
  int tid = threadIdx.x;
  int wave = tid >> 6, lane = tid & 63;
  int bid = blockIdx.x;
  int l = bid / nsb, sb = bid - l * nsb;
  int sub = sb * 4 + wave;
  int m0 = sub * 16;
  if (m0 >= M) return;
  int sel = (0xE54770 >> l) & 1;                 // per-lstm real/imag selection
  const unsigned short* xs = sel ? xi : xr;
  int n = lane & 15, q = lane >> 4;
  int mr = m0 + n; if (mr >= M) mr = M - 1;      // clamp A rows (stores guarded)
  const unsigned short* xrow = xs + (size_t)mr * 64;
  bf16x8 a0 = *(const bf16x8*)(xrow + q * 8);        // c = q*8+e
  bf16x8 a1 = *(const bf16x8*)(xrow + 32 + q * 8);   // c = 32+q*8+e
  // per-(q,r) output coords: m = m0 + q*4 + r -> (bl, t)
  int mq = m0 + q * 4;
  int bl = mq / 200, tt = mq - bl * 200;
  size_t ob[4]; bool okm[4];
  #pragma unroll
  for (int r = 0; r < 4; ++r) {
    okm[r] = (mq + r) < M;
    ob[r] = ((size_t)(l * 200 + tt) * NB + bl) * 64;
    ++tt; if (tt == 200) { tt = 0; ++bl; }
  }
  const unsigned short* wbase = wbf + l * 4096;
  #pragma unroll
  for (int jt = 0; jt < 4; ++jt) {               // j = jt*16 + n ; k=n, g=jt
    const unsigned short* wrow = wbase + (jt * 16 + n) * 64;
    bf16x8 b0 = *(const bf16x8*)(wrow + q * 8);
    bf16x8 b1 = *(const bf16x8*)(wrow + 32 + q * 8);
    f32x4 acc = {0.f, 0.f, 0.f, 0.f};
    acc = __builtin_amdgcn_mfma_f32_16x16x32_bf16(a0, b0, acc, 0, 0, 0);
    acc = __builtin_amdgcn_mfma_f32_16x16x32_bf16(a1, b1, acc, 0, 0, 0);
    float bias = bihh[l * 64 + jt * 16 + n];
    #pragma unroll
    for (int r = 0; r < 4; ++r)
      if (okm[r]) xg[ob[r] + n * 4 + jt] = __float2bfloat16(acc[r] + bias);
  }
}

// ---------------- kernel R: LSTM recurrence, one wave per chain.
// Row layout (j>>4): row0=i, row1=g(cell), row2=f, row3=o ; k=j&15.
// Matvec: 16 readlane (h wave-uniform, h[r] in lane r) + 4-way fmac tree.
// Gate exchange: 3 parallel __shfl_xor (16,32,48) -> every lane holds all 4
// activations -> 8 cndmask selects; c/h computed redundantly in all lanes.
__global__ __launch_bounds__(256) void k_lstm(const __hip_bfloat16* __restrict__ xg,
    const float* __restrict__ Whh, float* __restrict__ hbuf, int NB) {
  int tid = threadIdx.x;
  int wave = tid >> 6, j = tid & 63;
  int chain = blockIdx.x * 4 + wave;      // 24*NB chains, NB*6 blocks
  int l = chain / NB, b = chain - l * NB;
  int row = j >> 4, k = j & 15;
  int gi = ((row & 1) << 1) | (row >> 1); // row->gate col: 0,2,1,3 (i,g,f,o)
  const float* wrow = Whh + (size_t)l * 1024 + (gi * 16 + k) * 16;
  float4 w0 = ((const float4*)wrow)[0];
  float4 w1 = ((const float4*)wrow)[1];
  float4 w2 = ((const float4*)wrow)[2];
  float4 w3 = ((const float4*)wrow)[3];
  bool isg = (row == 1);
  bool m16 = (row & 1);                   // rows 1,3
  bool m32 = (row & 2);                   // rows 2,3
  bool row0 = (j < 16);
  const unsigned short* xgp = (const unsigned short*)xg;
  size_t tstride = (size_t)NB * 64;
  size_t idx0 = ((size_t)l * 200 * NB + b) * 64 + k * 4 + gi;  // [k][g] layout
  float* hptr = hbuf + ((size_t)l * NB + b) * 3200 + k;
  float h = 0.f, c = 0.f;
  unsigned short u = xgp[idx0];
  for (int t = 0; t < 200; ++t) {
    int tn = t < 199 ? t + 1 : 199;
    unsigned short unext = xgp[idx0 + (size_t)tn * tstride];  // prefetch
    float p = bf2f(u);
    // 4 parallel fmac chains on readlane-broadcast h
    float q0 = w0.x * rdlane(h, 0);
    q0 += w0.y * rdlane(h, 1);  q0 += w0.z * rdlane(h, 2);  q0 += w0.w * rdlane(h, 3);
    float q1 = w1.x * rdlane(h, 4);
    q1 += w1.y * rdlane(h, 5);  q1 += w1.z * rdlane(h, 6);  q1 += w1.w * rdlane(h, 7);
    float q2 = w2.x * rdlane(h, 8);
    q2 += w2.y * rdlane(h, 9);  q2 += w2.z * rdlane(h, 10); q2 += w2.w * rdlane(h, 11);
    float q3 = w3.x * rdlane(h, 12);
    q3 += w3.y * rdlane(h, 13); q3 += w3.z * rdlane(h, 14); q3 += w3.w * rdlane(h, 15);
    p += (q0 + q1) + (q2 + q3);
    // own-gate activation: sigmoid, or tanh = 2*sigmoid(2x)-1 for cell gate
    float xs2 = isg ? (p + p) : p;
    float s = __fdividef(1.f, 1.f + __expf(-xs2));
    float av = isg ? (s + s - 1.f) : s;
    // xor-butterfly: all three depend only on av -> one DS round-trip
    float b16v = __shfl_xor(av, 16, 64);
    float b32v = __shfl_xor(av, 32, 64);
    float b48v = __shfl_xor(av, 48, 64);
    // rows hold gates (i,g,f,o); {own,x16,x32,x48} covers all four
    float xia = m32 ? b32v : av;
    float xib = m32 ? b48v : b16v;
    float iv = m16 ? xib : xia;
    float gv = m16 ? xia : xib;
    float xfa = m32 ? av : b32v;
    float xfb = m32 ? b16v : b48v;
    float fv = m16 ? xfb : xfa;
    float ov = m16 ? xfa : xfb;
    c = fv * c + iv * gv;
    float s2 = __fdividef(1.f, 1.f + __expf(-2.f * c));
    h = ov * (s2 + s2 - 1.f);             // tanh(c), identical in all lanes of k
    if (row0) hptr[t * 16] = h;
    u = unext;
  }
}

// ---------------- kernel C: attention per (branch, bl). Multiplicative causal
// mask before softmax: masked s get weight exp(0); handled via suffix-V init.
__global__ __launch_bounds__(256) void k_attn(const float* __restrict__ hbuf,
                                              float* __restrict__ att, int NB) {
  __shared__ float Q[200][17];
  __shared__ float K[200][16];
  __shared__ float V[200][16];
  __shared__ float Vs[200][17];
  int bid = blockIdx.x;                 // 8 br x NB
  int br = bid / NB, b = bid - br * NB;
  int tid = threadIdx.x;
  const float* qg = hbuf + ((size_t)(br * 3 + 0) * NB + b) * 3200;
  const float* kg = hbuf + ((size_t)(br * 3 + 1) * NB + b) * 3200;
  const float* vg = hbuf + ((size_t)(br * 3 + 2) * NB + b) * 3200;
  for (int i = 0; i < 4; ++i) {         // 200 rows x 4 f4 each of Q,K,V
    int idx = tid + i * 256;
    if (idx < 800) {
      int t = idx >> 2, q = idx & 3;
      float4 a = *(const float4*)(qg + t * 16 + q * 4);
      Q[t][q*4+0] = a.x; Q[t][q*4+1] = a.y; Q[t][q*4+2] = a.z; Q[t][q*4+3] = a.w;
      *(float4*)&K[t][q * 4] = *(const float4*)(kg + t * 16 + q * 4);
      *(float4*)&V[t][q * 4] = *(const float4*)(vg + t * 16 + q * 4);
    }
  }
  __syncthreads();
  if (tid < 16) {                       // suffix sums of V
    float acc = 0.f;
    Vs[199][tid] = 0.f;
    for (int t = 198; t >= 0; --t) { acc += V[t + 1][tid]; Vs[t][tid] = acc; }
  }
  __syncthreads();
  if (tid < 200) {
    int t = tid;
    float q0[16], va[16];
    #pragma unroll
    for (int k = 0; k < 16; ++k) q0[k] = Q[t][k] * 0.25f;   // fold /sqrt(16)
    #pragma unroll
    for (int k = 0; k < 16; ++k) va[k] = Vs[t][k];          // masked: weight exp(0)=1
    float S = (float)(199 - t);
    for (int s = 0; s <= t; ++s) {
      float e = 0.f;
      #pragma unroll
      for (int k = 0; k < 16; ++k) e += q0[k] * K[s][k];
      float wgt = __expf(e);
      S += wgt;
      #pragma unroll
      for (int k = 0; k < 16; ++k) va[k] += wgt * V[s][k];
    }
    float inv = __fdividef(1.f, S);
    float* dst = att + (((size_t)br * NB + b) * 200 + t) * 16;
    #pragma unroll
    for (int q = 0; q < 4; ++q) {
      float4 v; v.x = va[q*4+0]*inv; v.y = va[q*4+1]*inv;
      v.z = va[q*4+2]*inv; v.w = va[q*4+3]*inv;
      *(float4*)(dst + q * 4) = v;
    }
  }
}

// ---------------- kernel D: combine branches + LN2 + complex linear + LN3 +
// PReLU + residual, with LDS transpose for coalesced [N,C,F,T,2] IO.
__global__ __launch_bounds__(256) void k_out(const float* __restrict__ att,
    const float* __restrict__ in,
    const float* __restrict__ ln2w, const float* __restrict__ ln2b,
    const float* __restrict__ lrw, const float* __restrict__ lrb,
    const float* __restrict__ liw, const float* __restrict__ lib,
    const float* __restrict__ ln3w, const float* __restrict__ ln3b,
    const float* __restrict__ pa, float* __restrict__ out, int b0, int NB) {
  __shared__ float as_[8][40][17];
  __shared__ float ys[40][2][17];
  __shared__ float zs[64][81];
  int bid = blockIdx.x;                 // NB nf-local x 5 tiles of 40 t
  int nfl = bid / 5, tile = bid - nfl * 5;
  int nf = b0 + nfl;
  int t0 = tile * 40;
  int n = nf / 100, f = nf - n * 100;
  int tid = threadIdx.x;
  for (int i = 0; i < 5; ++i) {         // att: 8 br x 40 t x 4 f4
    int idx = tid + i * 256;
    int br = idx / 160, r = idx - br * 160;
    int t = r >> 2, q = r & 3;
    float4 v = *(const float4*)(att + (((size_t)br * NB + nfl) * 200 + t0 + t) * 16 + q * 4);
    as_[br][t][q*4+0] = v.x; as_[br][t][q*4+1] = v.y;
    as_[br][t][q*4+2] = v.z; as_[br][t][q*4+3] = v.w;
  }
  __syncthreads();
  if (tid < 80) {                       // combine + LN2 per (t,ri)
    int t = tid >> 1, ri = tid & 1;
    float vv[16]; float s = 0.f, ss = 0.f;
    #pragma unroll
    for (int k = 0; k < 16; ++k) {
      float v;
      if (ri == 0) v = as_[0][t][k] - as_[1][t][k] - as_[2][t][k] - as_[3][t][k];
      else         v = as_[4][t][k] + as_[5][t][k] + as_[6][t][k] - as_[7][t][k];
      vv[k] = v; s += v; ss += v * v;
    }
    float mean = s * 0.0625f;
    float var  = ss * 0.0625f - mean * mean;
    float rstd = rsqrtf(var + 1e-5f);
    #pragma unroll
    for (int k = 0; k < 16; ++k)
      ys[t][ri][k] = (vv[k] - mean) * rstd * ln2w[k] + ln2b[k];
  }
  __syncthreads();
  // complex linear 16->64 + LN3 over c (wave = 64 lanes = c) + PReLU
  int wv = tid >> 6, cc = tid & 63;
  float lr[16], li[16];
  #pragma unroll
  for (int q = 0; q < 4; ++q) {
    float4 v = *(const float4*)(lrw + cc * 16 + q * 4);
    lr[q*4+0] = v.x; lr[q*4+1] = v.y; lr[q*4+2] = v.z; lr[q*4+3] = v.w;
    float4 u = *(const float4*)(liw + cc * 16 + q * 4);
    li[q*4+0] = u.x; li[q*4+1] = u.y; li[q*4+2] = u.z; li[q*4+3] = u.w;
  }
  float brc = lrb[cc], bic = lib[cc];
  float w3 = ln3w[cc], b3 = ln3b[cc];
  float aP = pa[0];
  for (int tt = wv; tt < 40; tt += 4) {
    float zr = brc - bic, zi = brc + bic;
    #pragma unroll
    for (int k = 0; k < 16; ++k) {
      float yr = ys[tt][0][k], yi = ys[tt][1][k];
      zr += yr * lr[k] - yi * li[k];
      zi += yi * lr[k] + yr * li[k];
    }
    float s1 = zr, s2 = zr * zr, s3 = zi, s4 = zi * zi;
    #pragma unroll
    for (int m = 1; m < 64; m <<= 1) {
      s1 += __shfl_xor(s1, m, 64);
      s2 += __shfl_xor(s2, m, 64);
      s3 += __shfl_xor(s3, m, 64);
      s4 += __shfl_xor(s4, m, 64);
    }
    float mr = s1 * 0.015625f, vr = s2 * 0.015625f - mr * mr;
    float mi = s3 * 0.015625f, vi = s4 * 0.015625f - mi * mi;
    float r1 = (zr - mr) * rsqrtf(vr + 1e-5f) * w3 + b3;
    float r2 = (zi - mi) * rsqrtf(vi + 1e-5f) * w3 + b3;
    r1 = r1 >= 0.f ? r1 : aP * r1;
    r2 = r2 >= 0.f ? r2 : aP * r2;
    zs[cc][tt * 2 + 0] = r1;
    zs[cc][tt * 2 + 1] = r2;
  }
  __syncthreads();
  for (int i = 0; i < 5; ++i) {         // residual + coalesced write
    int idx = tid + i * 256;            // 64 c x 20 f4
    int c = idx / 20, q = idx - c * 20;
    size_t gaddr = (size_t)((n * 64 + c) * 100 + f) * 400 + t0 * 2 + q * 4;
    float4 v = *(const float4*)(in + gaddr);
    float4 z;
    z.x = zs[c][q*4+0] + v.x; z.y = zs[c][q*4+1] + v.y;
    z.z = zs[c][q*4+2] + v.z; z.w = zs[c][q*4+3] + v.w;
    *(float4*)(out + gaddr) = z;
  }
}

extern "C" void kernel_launch(void* const* d_in, const int* in_sizes, int n_in,
                              void* d_out, int out_size, void* d_ws, size_t ws_size,
                              hipStream_t stream) {
  (void)in_sizes; (void)n_in; (void)out_size;
  const float* inputs = (const float*)d_in[0];
  const float* Wih  = (const float*)d_in[1];
  const float* Whh  = (const float*)d_in[2];
  const float* bih  = (const float*)d_in[3];
  const float* bhh  = (const float*)d_in[4];
  const float* ln1w = (const float*)d_in[5];
  const float* ln1b = (const float*)d_in[6];
  const float* ln2w = (const float*)d_in[7];
  const float* ln2b = (const float*)d_in[8];
  const float* lrw  = (const float*)d_in[9];
  const float* lrb  = (const float*)d_in[10];
  const float* liw  = (const float*)d_in[11];
  const float* lib  = (const float*)d_in[12];
  const float* ln3w = (const float*)d_in[13];
  const float* ln3b = (const float*)d_in[14];
  const float* pa   = (const float*)d_in[15];
  float* out = (float*)d_out;
  char* ws = (char*)d_ws;

  // pick largest chunk NB (400,200,100,50,25) whose buffers fit ws_size
  int NB = 400;
  while (NB > 25 && 204800ull + (size_t)NB * 1075200ull > ws_size) NB /= 2;
  int nch = 400 / NB;

  float* bihh = (float*)(ws + 0);                        // 6 KB
  unsigned short* wbf = (unsigned short*)(ws + 8192);    // 192 KB bf16 Wih
  size_t o_xr = 204800;
  size_t o_xi = o_xr + (size_t)NB * 25600;
  size_t o_xg = o_xi + (size_t)NB * 25600;
  size_t o_h  = o_xg + (size_t)NB * 614400;
  size_t o_at = o_h  + (size_t)NB * 307200;
  unsigned short* xr = (unsigned short*)(ws + o_xr);
  unsigned short* xi = (unsigned short*)(ws + o_xi);
  __hip_bfloat16* xg = (__hip_bfloat16*)(ws + o_xg);
  float* hbuf = (float*)(ws + o_h);
  float* att  = (float*)(ws + o_at);

  k_prep<<<384, 256, 0, stream>>>(bih, bhh, Wih, bihh, wbf);
  int M = NB * 200;
  int nsb = (M + 63) >> 6;              // 64 m-rows per block (4 waves x 16)
  for (int ch = 0; ch < nch; ++ch) {
    int b0 = ch * NB;
    k_ln1 <<<NB * 4,   256, 0, stream>>>(inputs, ln1w, ln1b, xr, xi, b0);
    k_xg  <<<24 * nsb, 256, 0, stream>>>(xr, xi, wbf, bihh, xg, M, NB, nsb);
    k_lstm<<<NB * 6,   256, 0, stream>>>(xg, Whh, hbuf, NB);   // 24*NB waves
    k_attn<<<8 * NB,   256, 0, stream>>>(hbuf, att, NB);
    k_out <<<NB * 5,   256, 0, stream>>>(att, inputs, ln2w, ln2b, lrw, lrb,
                                         liw, lib, ln3w, ln3b, pa, out, b0, NB);
  }
}

// Round 6
// 817.537 us; speedup vs baseline: 1.1441x; 1.0943x over previous
//
#include <hip/hip_runtime.h>
#include <hip/hip_bf16.h>

// Problem: N=4,C=64,F=100,T=200,H=16 ; B=N*F=400, BT=80000
// Pipeline per b-chunk (NB rows): ln1 (fp32->bf16 x) -> xg GEMM (MFMA bf16,
//   bf16 out, gate-permuted, coalesced ushort4 stores) -> LSTM recurrence
//   (4 chains/wave, 64 fmac/lane/step, named-register weights, 16 shfl
//   h-broadcast) -> attention (multiplicative causal mask BEFORE softmax,
//   suffix-V trick) -> combine+LN2+complex linear+LN3+PReLU+residual.
// ws: header 204800 B (bihh fp32 @0, Wih-bf16 @8192), then per chunk:
//   xr bf16 [NB][200][64], xi same, xg bf16 [24][200][NB][16][4],
//   h f32 [24][NB][200][16], att f32 [8][NB][200][16].
// Total = 204800 + NB*1,075,200.

typedef __attribute__((ext_vector_type(8))) short bf16x8;
typedef __attribute__((ext_vector_type(4))) float f32x4;

static __device__ __forceinline__ float bf2f(unsigned short u) {
  return __uint_as_float(((unsigned)u) << 16);
}
static __device__ __forceinline__ unsigned short f2bfu(float x) {
  __hip_bfloat16 h = __float2bfloat16(x);
  return *(unsigned short*)&h;
}
static __device__ __forceinline__ float sigf(float x) {
  return __fdividef(1.f, 1.f + __expf(-x));
}
static __device__ __forceinline__ float tanh_(float x) {
  return 1.f - __fdividef(2.f, __expf(2.f * x) + 1.f);  // safe at +-inf
}

// ---------------- kernel A: LN1 over C -> xr/xi bf16 [bl][t][c]
__global__ __launch_bounds__(256) void k_ln1(const float* __restrict__ in,
    const float* __restrict__ w, const float* __restrict__ bsh,
    unsigned short* __restrict__ xr, unsigned short* __restrict__ xi, int b0) {
  __shared__ float is[64][101];   // [c][(tloc,ri)]
  __shared__ float os[100][65];   // [(tloc,ri)][c]
  int bid = blockIdx.x;
  int nfl = bid >> 2, tile = bid & 3;         // NB nf-local x 4 tiles of 50 t
  int nf = b0 + nfl;
  int t0 = tile * 50;
  int n = nf / 100, f = nf - n * 100;
  int tid = threadIdx.x;
  for (int i = 0; i < 7; ++i) {               // 64 rows x 25 float4
    int idx = tid + i * 256;
    if (idx < 1600) {
      int c = idx / 25, q = idx - c * 25;
      float4 v = *(const float4*)(in + (size_t)((n * 64 + c) * 100 + f) * 400
                                  + t0 * 2 + q * 4);
      is[c][q*4+0] = v.x; is[c][q*4+1] = v.y; is[c][q*4+2] = v.z; is[c][q*4+3] = v.w;
    }
  }
  __syncthreads();
  if (tid < 100) {
    float s = 0.f, ss = 0.f;
    #pragma unroll
    for (int c = 0; c < 64; ++c) { float v = is[c][tid]; s += v; ss += v * v; }
    float mean = s * 0.015625f;
    float var  = ss * 0.015625f - mean * mean;
    float rstd = rsqrtf(var + 1e-5f);
    #pragma unroll
    for (int c = 0; c < 64; ++c)
      os[tid][c] = (is[c][tid] - mean) * rstd * w[c] + bsh[c];
  }
  __syncthreads();
  for (int ri = 0; ri < 2; ++ri) {
    unsigned short* dst = ri ? xi : xr;
    for (int i = 0; i < 4; ++i) {             // 50 rows x 16 ushort4 per ri
      int idx = tid + i * 256;
      if (idx < 800) {
        int t = idx >> 4, q = idx & 15;
        ushort4 v;
        v.x = f2bfu(os[t*2+ri][q*4+0]); v.y = f2bfu(os[t*2+ri][q*4+1]);
        v.z = f2bfu(os[t*2+ri][q*4+2]); v.w = f2bfu(os[t*2+ri][q*4+3]);
        *(ushort4*)(dst + ((size_t)nfl * 200 + t0 + t) * 64 + q * 4) = v;
      }
    }
  }
}

// ---------------- prep: bihh = bih + bhh ; wbf = bf16(Wih)
__global__ void k_prep(const float* __restrict__ bih, const float* __restrict__ bhh,
                       const float* __restrict__ Wih, float* __restrict__ bihh,
                       unsigned short* __restrict__ wbf) {
  int i = blockIdx.x * 256 + threadIdx.x;
  if (i < 1536) bihh[i] = bih[i] + bhh[i];
  if (i < 98304) wbf[i] = f2bfu(Wih[i]);
}

// ---------------- kernel B: xg = x_sel @ Wih[l]^T + bihh[l] via MFMA bf16.
// One wave = 16-row m-strip x all 64 j. A-frag: m=lane&15, k=quad*8+e.
// B-frag: n=lane&15, k=quad*8+e. D: col=lane&15, row=quad*4+r (verified by
// rounds 4-5 passing). Lane holds col n=k for every jt -> accumulate the 4
// gate results and store one coalesced ushort4 {i,f,g,o} per row.
__global__ __launch_bounds__(256) void k_xg(const unsigned short* __restrict__ xr,
    const unsigned short* __restrict__ xi, const unsigned short* __restrict__ wbf,
    const float* __restrict__ bihh, unsigned short* __restrict__ xg,
    int M, int NB, int nsb) {
  int tid = threadIdx.x;
  int wave = tid >> 6, lane = tid & 63;
  int bid = blockIdx.x;
  int l = bid / nsb, sb = bid - l * nsb;
  int sub = sb * 4 + wave;
  int m0 = sub * 16;
  if (m0 >= M) return;
  int sel = (0xE54770 >> l) & 1;                 // per-lstm real/imag selection
  const unsigned short* xs = sel ? xi : xr;
  int n = lane & 15, q = lane >> 4;
  int mr = m0 + n; if (mr >= M) mr = M - 1;      // clamp A rows (stores guarded)
  const unsigned short* xrow = xs + (size_t)mr * 64;
  bf16x8 a0 = *(const bf16x8*)(xrow + q * 8);        // c = q*8+e
  bf16x8 a1 = *(const bf16x8*)(xrow + 32 + q * 8);   // c = 32+q*8+e
  // per-(q,r) output coords: m = m0 + q*4 + r -> (bl, t)
  int mq = m0 + q * 4;
  int bl = mq / 200, tt = mq - bl * 200;
  size_t ob[4]; bool okm[4];
  #pragma unroll
  for (int r = 0; r < 4; ++r) {
    okm[r] = (mq + r) < M;
    ob[r] = ((size_t)(l * 200 + tt) * NB + bl) * 64;
    ++tt; if (tt == 200) { tt = 0; ++bl; }
  }
  const unsigned short* wbase = wbf + l * 4096;
  f32x4 acc[4];
  float bi[4];
  #pragma unroll
  for (int jt = 0; jt < 4; ++jt) {               // j = jt*16 + n ; k=n, g=jt
    const unsigned short* wrow = wbase + (jt * 16 + n) * 64;
    bf16x8 b0 = *(const bf16x8*)(wrow + q * 8);
    bf16x8 b1 = *(const bf16x8*)(wrow + 32 + q * 8);
    f32x4 a = {0.f, 0.f, 0.f, 0.f};
    a = __builtin_amdgcn_mfma_f32_16x16x32_bf16(a0, b0, a, 0, 0, 0);
    acc[jt] = __builtin_amdgcn_mfma_f32_16x16x32_bf16(a1, b1, a, 0, 0, 0);
    bi[jt] = bihh[l * 64 + jt * 16 + n];
  }
  #pragma unroll
  for (int r = 0; r < 4; ++r) {
    if (!okm[r]) continue;
    ushort4 o;
    o.x = f2bfu(acc[0][r] + bi[0]);
    o.y = f2bfu(acc[1][r] + bi[1]);
    o.z = f2bfu(acc[2][r] + bi[2]);
    o.w = f2bfu(acc[3][r] + bi[3]);
    *(ushort4*)(xg + ob[r] + n * 4) = o;         // coalesced 8B store
  }
}

// ---------------- kernel R: LSTM recurrence. 1 wave per block = 4 chains.
// lane = (bl=lane>>4 chain, k=lane&15). Each lane computes ALL 4 gate
// pre-acts for its (chain,k): 64 fmac/lane/step (16 per chain-step, ~60%
// fmac density). Weights in 16 NAMED float4s (no indexed array -> no
// scratch). h broadcast: 16 __shfl within the 16-lane group.
__global__ __launch_bounds__(64) void k_lstm(const unsigned short* __restrict__ xg,
    const float* __restrict__ Whh, float* __restrict__ hbuf, int NB) {
  int lane = threadIdx.x;
  int bl = lane >> 4, k = lane & 15;
  int chain = blockIdx.x * 4 + bl;        // 24*NB chains, 6*NB blocks
  int l = chain / NB, b = chain - l * NB;
  int grp = lane & 48;
  const float* W = Whh + (size_t)l * 1024;
  const float* wi = W + k * 16;           // gate i row
  const float* wf = W + (16 + k) * 16;    // gate f row
  const float* wg = W + (32 + k) * 16;    // gate g row
  const float* wo = W + (48 + k) * 16;    // gate o row
  float4 wa0 = ((const float4*)wi)[0], wa1 = ((const float4*)wi)[1],
         wa2 = ((const float4*)wi)[2], wa3 = ((const float4*)wi)[3];
  float4 wb0 = ((const float4*)wf)[0], wb1 = ((const float4*)wf)[1],
         wb2 = ((const float4*)wf)[2], wb3 = ((const float4*)wf)[3];
  float4 wc0 = ((const float4*)wg)[0], wc1 = ((const float4*)wg)[1],
         wc2 = ((const float4*)wg)[2], wc3 = ((const float4*)wg)[3];
  float4 wd0 = ((const float4*)wo)[0], wd1 = ((const float4*)wo)[1],
         wd2 = ((const float4*)wo)[2], wd3 = ((const float4*)wo)[3];
  const unsigned short* xgp = xg + ((size_t)l * 200 * NB + b) * 64 + k * 4;
  size_t tstride = (size_t)NB * 64;       // ushorts per t step
  float* hp = hbuf + ((size_t)l * NB + b) * 3200 + k;
  float h = 0.f, c = 0.f;
  ushort4 u = *(const ushort4*)xgp;
  for (int t = 0; t < 200; ++t) {
    const unsigned short* pn = xgp + (size_t)(t < 199 ? t + 1 : 199) * tstride;
    ushort4 un = *(const ushort4*)pn;     // prefetch
    float p0 = bf2f(u.x), p1 = bf2f(u.y), p2 = bf2f(u.z), p3 = bf2f(u.w);
    float hv;
    hv = __shfl(h, grp + 0, 64);
    p0 += wa0.x*hv; p1 += wb0.x*hv; p2 += wc0.x*hv; p3 += wd0.x*hv;
    hv = __shfl(h, grp + 1, 64);
    p0 += wa0.y*hv; p1 += wb0.y*hv; p2 += wc0.y*hv; p3 += wd0.y*hv;
    hv = __shfl(h, grp + 2, 64);
    p0 += wa0.z*hv; p1 += wb0.z*hv; p2 += wc0.z*hv; p3 += wd0.z*hv;
    hv = __shfl(h, grp + 3, 64);
    p0 += wa0.w*hv; p1 += wb0.w*hv; p2 += wc0.w*hv; p3 += wd0.w*hv;
    hv = __shfl(h, grp + 4, 64);
    p0 += wa1.x*hv; p1 += wb1.x*hv; p2 += wc1.x*hv; p3 += wd1.x*hv;
    hv = __shfl(h, grp + 5, 64);
    p0 += wa1.y*hv; p1 += wb1.y*hv; p2 += wc1.y*hv; p3 += wd1.y*hv;
    hv = __shfl(h, grp + 6, 64);
    p0 += wa1.z*hv; p1 += wb1.z*hv; p2 += wc1.z*hv; p3 += wd1.z*hv;
    hv = __shfl(h, grp + 7, 64);
    p0 += wa1.w*hv; p1 += wb1.w*hv; p2 += wc1.w*hv; p3 += wd1.w*hv;
    hv = __shfl(h, grp + 8, 64);
    p0 += wa2.x*hv; p1 += wb2.x*hv; p2 += wc2.x*hv; p3 += wd2.x*hv;
    hv = __shfl(h, grp + 9, 64);
    p0 += wa2.y*hv; p1 += wb2.y*hv; p2 += wc2.y*hv; p3 += wd2.y*hv;
    hv = __shfl(h, grp + 10, 64);
    p0 += wa2.z*hv; p1 += wb2.z*hv; p2 += wc2.z*hv; p3 += wd2.z*hv;
    hv = __shfl(h, grp + 11, 64);
    p0 += wa2.w*hv; p1 += wb2.w*hv; p2 += wc2.w*hv; p3 += wd2.w*hv;
    hv = __shfl(h, grp + 12, 64);
    p0 += wa3.x*hv; p1 += wb3.x*hv; p2 += wc3.x*hv; p3 += wd3.x*hv;
    hv = __shfl(h, grp + 13, 64);
    p0 += wa3.y*hv; p1 += wb3.y*hv; p2 += wc3.y*hv; p3 += wd3.y*hv;
    hv = __shfl(h, grp + 14, 64);
    p0 += wa3.z*hv; p1 += wb3.z*hv; p2 += wc3.z*hv; p3 += wd3.z*hv;
    hv = __shfl(h, grp + 15, 64);
    p0 += wa3.w*hv; p1 += wb3.w*hv; p2 += wc3.w*hv; p3 += wd3.w*hv;
    float ig = sigf(p0), fg = sigf(p1), gg = tanh_(p2), og = sigf(p3);
    c = fg * c + ig * gg;
    h = og * tanh_(c);
    hp[t * 16] = h;                       // every lane owns a unique (chain,k)
    u = un;
  }
}

// ---------------- kernel C: attention per (branch, bl). Multiplicative causal
// mask before softmax: masked s get weight exp(0); handled via suffix-V init.
__global__ __launch_bounds__(256) void k_attn(const float* __restrict__ hbuf,
                                              float* __restrict__ att, int NB) {
  __shared__ float Q[200][17];
  __shared__ float K[200][16];
  __shared__ float V[200][16];
  __shared__ float Vs[200][17];
  int bid = blockIdx.x;                 // 8 br x NB
  int br = bid / NB, b = bid - br * NB;
  int tid = threadIdx.x;
  const float* qg = hbuf + ((size_t)(br * 3 + 0) * NB + b) * 3200;
  const float* kg = hbuf + ((size_t)(br * 3 + 1) * NB + b) * 3200;
  const float* vg = hbuf + ((size_t)(br * 3 + 2) * NB + b) * 3200;
  for (int i = 0; i < 4; ++i) {         // 200 rows x 4 f4 each of Q,K,V
    int idx = tid + i * 256;
    if (idx < 800) {
      int t = idx >> 2, q = idx & 3;
      float4 a = *(const float4*)(qg + t * 16 + q * 4);
      Q[t][q*4+0] = a.x; Q[t][q*4+1] = a.y; Q[t][q*4+2] = a.z; Q[t][q*4+3] = a.w;
      *(float4*)&K[t][q * 4] = *(const float4*)(kg + t * 16 + q * 4);
      *(float4*)&V[t][q * 4] = *(const float4*)(vg + t * 16 + q * 4);
    }
  }
  __syncthreads();
  if (tid < 16) {                       // suffix sums of V
    float acc = 0.f;
    Vs[199][tid] = 0.f;
    for (int t = 198; t >= 0; --t) { acc += V[t + 1][tid]; Vs[t][tid] = acc; }
  }
  __syncthreads();
  if (tid < 200) {
    int t = tid;
    float q0[16], va[16];
    #pragma unroll
    for (int k = 0; k < 16; ++k) q0[k] = Q[t][k] * 0.25f;   // fold /sqrt(16)
    #pragma unroll
    for (int k = 0; k < 16; ++k) va[k] = Vs[t][k];          // masked: weight exp(0)=1
    float S = (float)(199 - t);
    for (int s = 0; s <= t; ++s) {
      float e = 0.f;
      #pragma unroll
      for (int k = 0; k < 16; ++k) e += q0[k] * K[s][k];
      float wgt = __expf(e);
      S += wgt;
      #pragma unroll
      for (int k = 0; k < 16; ++k) va[k] += wgt * V[s][k];
    }
    float inv = __fdividef(1.f, S);
    float* dst = att + (((size_t)br * NB + b) * 200 + t) * 16;
    #pragma unroll
    for (int q = 0; q < 4; ++q) {
      float4 v; v.x = va[q*4+0]*inv; v.y = va[q*4+1]*inv;
      v.z = va[q*4+2]*inv; v.w = va[q*4+3]*inv;
      *(float4*)(dst + q * 4) = v;
    }
  }
}

// ---------------- kernel D: combine branches + LN2 + complex linear + LN3 +
// PReLU + residual, with LDS transpose for coalesced [N,C,F,T,2] IO.
__global__ __launch_bounds__(256) void k_out(const float* __restrict__ att,
    const float* __restrict__ in,
    const float* __restrict__ ln2w, const float* __restrict__ ln2b,
    const float* __restrict__ lrw, const float* __restrict__ lrb,
    const float* __restrict__ liw, const float* __restrict__ lib,
    const float* __restrict__ ln3w, const float* __restrict__ ln3b,
    const float* __restrict__ pa, float* __restrict__ out, int b0, int NB) {
  __shared__ float as_[8][40][17];
  __shared__ float ys[40][2][17];
  __shared__ float zs[64][81];
  int bid = blockIdx.x;                 // NB nf-local x 5 tiles of 40 t
  int nfl = bid / 5, tile = bid - nfl * 5;
  int nf = b0 + nfl;
  int t0 = tile * 40;
  int n = nf / 100, f = nf - n * 100;
  int tid = threadIdx.x;
  for (int i = 0; i < 5; ++i) {         // att: 8 br x 40 t x 4 f4
    int idx = tid + i * 256;
    int br = idx / 160, r = idx - br * 160;
    int t = r >> 2, q = r & 3;
    float4 v = *(const float4*)(att + (((size_t)br * NB + nfl) * 200 + t0 + t) * 16 + q * 4);
    as_[br][t][q*4+0] = v.x; as_[br][t][q*4+1] = v.y;
    as_[br][t][q*4+2] = v.z; as_[br][t][q*4+3] = v.w;
  }
  __syncthreads();
  if (tid < 80) {                       // combine + LN2 per (t,ri)
    int t = tid >> 1, ri = tid & 1;
    float vv[16]; float s = 0.f, ss = 0.f;
    #pragma unroll
    for (int k = 0; k < 16; ++k) {
      float v;
      if (ri == 0) v = as_[0][t][k] - as_[1][t][k] - as_[2][t][k] - as_[3][t][k];
      else         v = as_[4][t][k] + as_[5][t][k] + as_[6][t][k] - as_[7][t][k];
      vv[k] = v; s += v; ss += v * v;
    }
    float mean = s * 0.0625f;
    float var  = ss * 0.0625f - mean * mean;
    float rstd = rsqrtf(var + 1e-5f);
    #pragma unroll
    for (int k = 0; k < 16; ++k)
      ys[t][ri][k] = (vv[k] - mean) * rstd * ln2w[k] + ln2b[k];
  }
  __syncthreads();
  // complex linear 16->64 + LN3 over c (wave = 64 lanes = c) + PReLU
  int wv = tid >> 6, cc = tid & 63;
  float lr[16], li[16];
  #pragma unroll
  for (int q = 0; q < 4; ++q) {
    float4 v = *(const float4*)(lrw + cc * 16 + q * 4);
    lr[q*4+0] = v.x; lr[q*4+1] = v.y; lr[q*4+2] = v.z; lr[q*4+3] = v.w;
    float4 u = *(const float4*)(liw + cc * 16 + q * 4);
    li[q*4+0] = u.x; li[q*4+1] = u.y; li[q*4+2] = u.z; li[q*4+3] = u.w;
  }
  float brc = lrb[cc], bic = lib[cc];
  float w3 = ln3w[cc], b3 = ln3b[cc];
  float aP = pa[0];
  for (int tt = wv; tt < 40; tt += 4) {
    float zr = brc - bic, zi = brc + bic;
    #pragma unroll
    for (int k = 0; k < 16; ++k) {
      float yr = ys[tt][0][k], yi = ys[tt][1][k];
      zr += yr * lr[k] - yi * li[k];
      zi += yi * lr[k] + yr * li[k];
    }
    float s1 = zr, s2 = zr * zr, s3 = zi, s4 = zi * zi;
    #pragma unroll
    for (int m = 1; m < 64; m <<= 1) {
      s1 += __shfl_xor(s1, m, 64);
      s2 += __shfl_xor(s2, m, 64);
      s3 += __shfl_xor(s3, m, 64);
      s4 += __shfl_xor(s4, m, 64);
    }
    float mr = s1 * 0.015625f, vr = s2 * 0.015625f - mr * mr;
    float mi = s3 * 0.015625f, vi = s4 * 0.015625f - mi * mi;
    float r1 = (zr - mr) * rsqrtf(vr + 1e-5f) * w3 + b3;
    float r2 = (zi - mi) * rsqrtf(vi + 1e-5f) * w3 + b3;
    r1 = r1 >= 0.f ? r1 : aP * r1;
    r2 = r2 >= 0.f ? r2 : aP * r2;
    zs[cc][tt * 2 + 0] = r1;
    zs[cc][tt * 2 + 1] = r2;
  }
  __syncthreads();
  for (int i = 0; i < 5; ++i) {         // residual + coalesced write
    int idx = tid + i * 256;            // 64 c x 20 f4
    int c = idx / 20, q = idx - c * 20;
    size_t gaddr = (size_t)((n * 64 + c) * 100 + f) * 400 + t0 * 2 + q * 4;
    float4 v = *(const float4*)(in + gaddr);
    float4 z;
    z.x = zs[c][q*4+0] + v.x; z.y = zs[c][q*4+1] + v.y;
    z.z = zs[c][q*4+2] + v.z; z.w = zs[c][q*4+3] + v.w;
    *(float4*)(out + gaddr) = z;
  }
}

extern "C" void kernel_launch(void* const* d_in, const int* in_sizes, int n_in,
                              void* d_out, int out_size, void* d_ws, size_t ws_size,
                              hipStream_t stream) {
  (void)in_sizes; (void)n_in; (void)out_size;
  const float* inputs = (const float*)d_in[0];
  const float* Wih  = (const float*)d_in[1];
  const float* Whh  = (const float*)d_in[2];
  const float* bih  = (const float*)d_in[3];
  const float* bhh  = (const float*)d_in[4];
  const float* ln1w = (const float*)d_in[5];
  const float* ln1b = (const float*)d_in[6];
  const float* ln2w = (const float*)d_in[7];
  const float* ln2b = (const float*)d_in[8];
  const float* lrw  = (const float*)d_in[9];
  const float* lrb  = (const float*)d_in[10];
  const float* liw  = (const float*)d_in[11];
  const float* lib  = (const float*)d_in[12];
  const float* ln3w = (const float*)d_in[13];
  const float* ln3b = (const float*)d_in[14];
  const float* pa   = (const float*)d_in[15];
  float* out = (float*)d_out;
  char* ws = (char*)d_ws;

  // pick largest chunk NB (400,200,100,50,25) whose buffers fit ws_size
  int NB = 400;
  while (NB > 25 && 204800ull + (size_t)NB * 1075200ull > ws_size) NB /= 2;
  int nch = 400 / NB;

  float* bihh = (float*)(ws + 0);                        // 6 KB
  unsigned short* wbf = (unsigned short*)(ws + 8192);    // 192 KB bf16 Wih
  size_t o_xr = 204800;
  size_t o_xi = o_xr + (size_t)NB * 25600;
  size_t o_xg = o_xi + (size_t)NB * 25600;
  size_t o_h  = o_xg + (size_t)NB * 614400;
  size_t o_at = o_h  + (size_t)NB * 307200;
  unsigned short* xr = (unsigned short*)(ws + o_xr);
  unsigned short* xi = (unsigned short*)(ws + o_xi);
  unsigned short* xg = (unsigned short*)(ws + o_xg);
  float* hbuf = (float*)(ws + o_h);
  float* att  = (float*)(ws + o_at);

  k_prep<<<384, 256, 0, stream>>>(bih, bhh, Wih, bihh, wbf);
  int M = NB * 200;
  int nsb = (M + 63) >> 6;              // 64 m-rows per block (4 waves x 16)
  for (int ch = 0; ch < nch; ++ch) {
    int b0 = ch * NB;
    k_ln1 <<<NB * 4,   256, 0, stream>>>(inputs, ln1w, ln1b, xr, xi, b0);
    k_xg  <<<24 * nsb, 256, 0, stream>>>(xr, xi, wbf, bihh, xg, M, NB, nsb);
    k_lstm<<<NB * 6,    64, 0, stream>>>(xg, Whh, hbuf, NB);   // 1 wave = 4 chains
    k_attn<<<8 * NB,   256, 0, stream>>>(hbuf, att, NB);
    k_out <<<NB * 5,   256, 0, stream>>>(att, inputs, ln2w, ln2b, lrw, lrb,
                                         liw, lib, ln3w, ln3b, pa, out, b0, NB);
  }
}

// Round 7
// 770.997 us; speedup vs baseline: 1.2132x; 1.0604x over previous
//
#include <hip/hip_runtime.h>
#include <hip/hip_bf16.h>

// Problem: N=4,C=64,F=100,T=200,H=16 ; B=N*F=400, BT=80000
// Pipeline per b-chunk (NB rows): ln1 (fp32->bf16 x) -> xg GEMM (MFMA bf16,
//   bf16 out, gate-permuted, coalesced ushort4 stores) -> LSTM recurrence
//   (4 chains/wave, packed f32x2 gate math, named-register weights,
//   depth-4 xg prefetch, 16 shfl h-broadcast) -> attention (multiplicative
//   causal mask BEFORE softmax, suffix-V trick) -> combine+LN2+complex
//   linear+LN3+PReLU+residual.
// ws: header 204800 B (bihh fp32 @0, Wih-bf16 @8192), then per chunk:
//   xr bf16 [NB][200][64], xi same, xg bf16 [24][200][NB][16][4],
//   h f32 [24][NB][200][16], att f32 [8][NB][200][16].
// Total = 204800 + NB*1,075,200.

typedef __attribute__((ext_vector_type(8))) short bf16x8;
typedef __attribute__((ext_vector_type(4))) float f32x4;
typedef __attribute__((ext_vector_type(2))) float f32x2;

static __device__ __forceinline__ float bf2f(unsigned short u) {
  return __uint_as_float(((unsigned)u) << 16);
}
static __device__ __forceinline__ unsigned short f2bfu(float x) {
  __hip_bfloat16 h = __float2bfloat16(x);
  return *(unsigned short*)&h;
}
static __device__ __forceinline__ float sigf(float x) {
  return __fdividef(1.f, 1.f + __expf(-x));
}
static __device__ __forceinline__ float tanh_(float x) {
  return 1.f - __fdividef(2.f, __expf(2.f * x) + 1.f);  // safe at +-inf
}

// ---------------- kernel A: LN1 over C -> xr/xi bf16 [bl][t][c]
__global__ __launch_bounds__(256) void k_ln1(const float* __restrict__ in,
    const float* __restrict__ w, const float* __restrict__ bsh,
    unsigned short* __restrict__ xr, unsigned short* __restrict__ xi, int b0) {
  __shared__ float is[64][101];   // [c][(tloc,ri)]
  __shared__ float os[100][65];   // [(tloc,ri)][c]
  int bid = blockIdx.x;
  int nfl = bid >> 2, tile = bid & 3;         // NB nf-local x 4 tiles of 50 t
  int nf = b0 + nfl;
  int t0 = tile * 50;
  int n = nf / 100, f = nf - n * 100;
  int tid = threadIdx.x;
  for (int i = 0; i < 7; ++i) {               // 64 rows x 25 float4
    int idx = tid + i * 256;
    if (idx < 1600) {
      int c = idx / 25, q = idx - c * 25;
      float4 v = *(const float4*)(in + (size_t)((n * 64 + c) * 100 + f) * 400
                                  + t0 * 2 + q * 4);
      is[c][q*4+0] = v.x; is[c][q*4+1] = v.y; is[c][q*4+2] = v.z; is[c][q*4+3] = v.w;
    }
  }
  __syncthreads();
  if (tid < 100) {
    float s = 0.f, ss = 0.f;
    #pragma unroll
    for (int c = 0; c < 64; ++c) { float v = is[c][tid]; s += v; ss += v * v; }
    float mean = s * 0.015625f;
    float var  = ss * 0.015625f - mean * mean;
    float rstd = rsqrtf(var + 1e-5f);
    #pragma unroll
    for (int c = 0; c < 64; ++c)
      os[tid][c] = (is[c][tid] - mean) * rstd * w[c] + bsh[c];
  }
  __syncthreads();
  for (int ri = 0; ri < 2; ++ri) {
    unsigned short* dst = ri ? xi : xr;
    for (int i = 0; i < 4; ++i) {             // 50 rows x 16 ushort4 per ri
      int idx = tid + i * 256;
      if (idx < 800) {
        int t = idx >> 4, q = idx & 15;
        ushort4 v;
        v.x = f2bfu(os[t*2+ri][q*4+0]); v.y = f2bfu(os[t*2+ri][q*4+1]);
        v.z = f2bfu(os[t*2+ri][q*4+2]); v.w = f2bfu(os[t*2+ri][q*4+3]);
        *(ushort4*)(dst + ((size_t)nfl * 200 + t0 + t) * 64 + q * 4) = v;
      }
    }
  }
}

// ---------------- prep: bihh = bih + bhh ; wbf = bf16(Wih)
__global__ void k_prep(const float* __restrict__ bih, const float* __restrict__ bhh,
                       const float* __restrict__ Wih, float* __restrict__ bihh,
                       unsigned short* __restrict__ wbf) {
  int i = blockIdx.x * 256 + threadIdx.x;
  if (i < 1536) bihh[i] = bih[i] + bhh[i];
  if (i < 98304) wbf[i] = f2bfu(Wih[i]);
}

// ---------------- kernel B: xg = x_sel @ Wih[l]^T + bihh[l] via MFMA bf16.
// One wave = 16-row m-strip x all 64 j. A-frag: m=lane&15, k=quad*8+e.
// B-frag: n=lane&15, k=quad*8+e. D: col=lane&15, row=quad*4+r. Lane holds
// col n=k for every jt -> accumulate 4 gate results, one ushort4 store/row.
__global__ __launch_bounds__(256) void k_xg(const unsigned short* __restrict__ xr,
    const unsigned short* __restrict__ xi, const unsigned short* __restrict__ wbf,
    const float* __restrict__ bihh, unsigned short* __restrict__ xg,
    int M, int NB, int nsb) {
  int tid = threadIdx.x;
  int wave = tid >> 6, lane = tid & 63;
  int bid = blockIdx.x;
  int l = bid / nsb, sb = bid - l * nsb;
  int sub = sb * 4 + wave;
  int m0 = sub * 16;
  if (m0 >= M) return;
  int sel = (0xE54770 >> l) & 1;                 // per-lstm real/imag selection
  const unsigned short* xs = sel ? xi : xr;
  int n = lane & 15, q = lane >> 4;
  int mr = m0 + n; if (mr >= M) mr = M - 1;      // clamp A rows (stores guarded)
  const unsigned short* xrow = xs + (size_t)mr * 64;
  bf16x8 a0 = *(const bf16x8*)(xrow + q * 8);        // c = q*8+e
  bf16x8 a1 = *(const bf16x8*)(xrow + 32 + q * 8);   // c = 32+q*8+e
  int mq = m0 + q * 4;
  int bl = mq / 200, tt = mq - bl * 200;
  size_t ob[4]; bool okm[4];
  #pragma unroll
  for (int r = 0; r < 4; ++r) {
    okm[r] = (mq + r) < M;
    ob[r] = ((size_t)(l * 200 + tt) * NB + bl) * 64;
    ++tt; if (tt == 200) { tt = 0; ++bl; }
  }
  const unsigned short* wbase = wbf + l * 4096;
  f32x4 acc[4];
  float bi[4];
  #pragma unroll
  for (int jt = 0; jt < 4; ++jt) {               // j = jt*16 + n ; k=n, g=jt
    const unsigned short* wrow = wbase + (jt * 16 + n) * 64;
    bf16x8 b0 = *(const bf16x8*)(wrow + q * 8);
    bf16x8 b1 = *(const bf16x8*)(wrow + 32 + q * 8);
    f32x4 a = {0.f, 0.f, 0.f, 0.f};
    a = __builtin_amdgcn_mfma_f32_16x16x32_bf16(a0, b0, a, 0, 0, 0);
    acc[jt] = __builtin_amdgcn_mfma_f32_16x16x32_bf16(a1, b1, a, 0, 0, 0);
    bi[jt] = bihh[l * 64 + jt * 16 + n];
  }
  #pragma unroll
  for (int r = 0; r < 4; ++r) {
    if (!okm[r]) continue;
    ushort4 o;
    o.x = f2bfu(acc[0][r] + bi[0]);
    o.y = f2bfu(acc[1][r] + bi[1]);
    o.z = f2bfu(acc[2][r] + bi[2]);
    o.w = f2bfu(acc[3][r] + bi[3]);
    *(ushort4*)(xg + ob[r] + n * 4) = o;         // coalesced 8B store
  }
}

// ---------------- kernel R: LSTM recurrence. 1 wave per block = 4 chains.
// lane=(bl=lane>>4 chain, k=lane&15). Lane computes all 4 gate pre-acts as
// two f32x2 (packed-fma-friendly). Weights in 32 NAMED f32x2 regs;
// __launch_bounds__(64,2) gives a 256-VGPR budget so the compiler keeps
// them resident (r6's VGPR=64 proved demotion). Depth-4 xg prefetch.
__global__ __launch_bounds__(64, 2) void k_lstm(const unsigned short* __restrict__ xg,
    const float* __restrict__ Whh, float* __restrict__ hbuf, int NB) {
  int lane = threadIdx.x;
  int bl = lane >> 4, k = lane & 15;
  int chain = blockIdx.x * 4 + bl;        // 24*NB chains, 6*NB blocks
  int l = chain / NB, b = chain - l * NB;
  int grp = lane & 48;
  const float* W = Whh + (size_t)l * 1024;
  const float* wi = W + k * 16;           // gate i row
  const float* wf = W + (16 + k) * 16;    // gate f row
  const float* wg = W + (32 + k) * 16;    // gate g row
  const float* wo = W + (48 + k) * 16;    // gate o row
#define DECLW(i) f32x2 wa##i = {wi[i], wf[i]}; f32x2 wb##i = {wg[i], wo[i]};
  DECLW(0) DECLW(1) DECLW(2) DECLW(3) DECLW(4) DECLW(5) DECLW(6) DECLW(7)
  DECLW(8) DECLW(9) DECLW(10) DECLW(11) DECLW(12) DECLW(13) DECLW(14) DECLW(15)
#undef DECLW
  const unsigned short* xgp = xg + ((size_t)l * 200 * NB + b) * 64 + k * 4;
  size_t tstride = (size_t)NB * 64;       // ushorts per t step
  float* hp = hbuf + ((size_t)l * NB + b) * 3200 + k;
  float h = 0.f, c = 0.f;
  ushort4 b0 = *(const ushort4*)(xgp);
  ushort4 b1 = *(const ushort4*)(xgp + tstride);
  ushort4 b2 = *(const ushort4*)(xgp + 2 * tstride);
  ushort4 b3 = *(const ushort4*)(xgp + 3 * tstride);
  int tcur = 0;
#define STAGE(i) { float hv_ = __shfl(h, grp + i, 64); \
  f32x2 hh_ = {hv_, hv_}; p01 += wa##i * hh_; p23 += wb##i * hh_; }
#define LSTEP(BUF, TN) { \
  f32x2 p01 = {bf2f(BUF.x), bf2f(BUF.y)}; \
  f32x2 p23 = {bf2f(BUF.z), bf2f(BUF.w)}; \
  STAGE(0) STAGE(1) STAGE(2) STAGE(3) STAGE(4) STAGE(5) STAGE(6) STAGE(7) \
  STAGE(8) STAGE(9) STAGE(10) STAGE(11) STAGE(12) STAGE(13) STAGE(14) STAGE(15) \
  float ig_ = sigf(p01.x), fg_ = sigf(p01.y); \
  float gg_ = tanh_(p23.x), og_ = sigf(p23.y); \
  c = fg_ * c + ig_ * gg_; \
  h = og_ * tanh_(c); \
  hp[tcur * 16] = h; ++tcur; \
  BUF = *(const ushort4*)(xgp + (size_t)(TN) * tstride); }
  for (int it = 0; it < 50; ++it) {
    int t4 = it * 4;
    int n0 = t4 + 4; if (n0 > 199) n0 = 199;
    int n1 = t4 + 5; if (n1 > 199) n1 = 199;
    int n2 = t4 + 6; if (n2 > 199) n2 = 199;
    int n3 = t4 + 7; if (n3 > 199) n3 = 199;
    LSTEP(b0, n0)
    LSTEP(b1, n1)
    LSTEP(b2, n2)
    LSTEP(b3, n3)
  }
#undef STAGE
#undef LSTEP
}

// ---------------- kernel C: attention per (branch, bl). Multiplicative causal
// mask before softmax: masked s get weight exp(0); handled via suffix-V init.
__global__ __launch_bounds__(256) void k_attn(const float* __restrict__ hbuf,
                                              float* __restrict__ att, int NB) {
  __shared__ float Q[200][17];
  __shared__ float K[200][16];
  __shared__ float V[200][16];
  __shared__ float Vs[200][17];
  int bid = blockIdx.x;                 // 8 br x NB
  int br = bid / NB, b = bid - br * NB;
  int tid = threadIdx.x;
  const float* qg = hbuf + ((size_t)(br * 3 + 0) * NB + b) * 3200;
  const float* kg = hbuf + ((size_t)(br * 3 + 1) * NB + b) * 3200;
  const float* vg = hbuf + ((size_t)(br * 3 + 2) * NB + b) * 3200;
  for (int i = 0; i < 4; ++i) {         // 200 rows x 4 f4 each of Q,K,V
    int idx = tid + i * 256;
    if (idx < 800) {
      int t = idx >> 2, q = idx & 3;
      float4 a = *(const float4*)(qg + t * 16 + q * 4);
      Q[t][q*4+0] = a.x; Q[t][q*4+1] = a.y; Q[t][q*4+2] = a.z; Q[t][q*4+3] = a.w;
      *(float4*)&K[t][q * 4] = *(const float4*)(kg + t * 16 + q * 4);
      *(float4*)&V[t][q * 4] = *(const float4*)(vg + t * 16 + q * 4);
    }
  }
  __syncthreads();
  if (tid < 16) {                       // suffix sums of V
    float acc = 0.f;
    Vs[199][tid] = 0.f;
    for (int t = 198; t >= 0; --t) { acc += V[t + 1][tid]; Vs[t][tid] = acc; }
  }
  __syncthreads();
  if (tid < 200) {
    int t = tid;
    float q0[16], va[16];
    #pragma unroll
    for (int k = 0; k < 16; ++k) q0[k] = Q[t][k] * 0.25f;   // fold /sqrt(16)
    #pragma unroll
    for (int k = 0; k < 16; ++k) va[k] = Vs[t][k];          // masked: weight exp(0)=1
    float S = (float)(199 - t);
    for (int s = 0; s <= t; ++s) {
      float e = 0.f;
      #pragma unroll
      for (int k = 0; k < 16; ++k) e += q0[k] * K[s][k];
      float wgt = __expf(e);
      S += wgt;
      #pragma unroll
      for (int k = 0; k < 16; ++k) va[k] += wgt * V[s][k];
    }
    float inv = __fdividef(1.f, S);
    float* dst = att + (((size_t)br * NB + b) * 200 + t) * 16;
    #pragma unroll
    for (int q = 0; q < 4; ++q) {
      float4 v; v.x = va[q*4+0]*inv; v.y = va[q*4+1]*inv;
      v.z = va[q*4+2]*inv; v.w = va[q*4+3]*inv;
      *(float4*)(dst + q * 4) = v;
    }
  }
}

// ---------------- kernel D: combine branches + LN2 + complex linear + LN3 +
// PReLU + residual, with LDS transpose for coalesced [N,C,F,T,2] IO.
__global__ __launch_bounds__(256) void k_out(const float* __restrict__ att,
    const float* __restrict__ in,
    const float* __restrict__ ln2w, const float* __restrict__ ln2b,
    const float* __restrict__ lrw, const float* __restrict__ lrb,
    const float* __restrict__ liw, const float* __restrict__ lib,
    const float* __restrict__ ln3w, const float* __restrict__ ln3b,
    const float* __restrict__ pa, float* __restrict__ out, int b0, int NB) {
  __shared__ float as_[8][40][17];
  __shared__ float ys[40][2][17];
  __shared__ float zs[64][81];
  int bid = blockIdx.x;                 // NB nf-local x 5 tiles of 40 t
  int nfl = bid / 5, tile = bid - nfl * 5;
  int nf = b0 + nfl;
  int t0 = tile * 40;
  int n = nf / 100, f = nf - n * 100;
  int tid = threadIdx.x;
  for (int i = 0; i < 5; ++i) {         // att: 8 br x 40 t x 4 f4
    int idx = tid + i * 256;
    int br = idx / 160, r = idx - br * 160;
    int t = r >> 2, q = r & 3;
    float4 v = *(const float4*)(att + (((size_t)br * NB + nfl) * 200 + t0 + t) * 16 + q * 4);
    as_[br][t][q*4+0] = v.x; as_[br][t][q*4+1] = v.y;
    as_[br][t][q*4+2] = v.z; as_[br][t][q*4+3] = v.w;
  }
  __syncthreads();
  if (tid < 80) {                       // combine + LN2 per (t,ri)
    int t = tid >> 1, ri = tid & 1;
    float vv[16]; float s = 0.f, ss = 0.f;
    #pragma unroll
    for (int k = 0; k < 16; ++k) {
      float v;
      if (ri == 0) v = as_[0][t][k] - as_[1][t][k] - as_[2][t][k] - as_[3][t][k];
      else         v = as_[4][t][k] + as_[5][t][k] + as_[6][t][k] - as_[7][t][k];
      vv[k] = v; s += v; ss += v * v;
    }
    float mean = s * 0.0625f;
    float var  = ss * 0.0625f - mean * mean;
    float rstd = rsqrtf(var + 1e-5f);
    #pragma unroll
    for (int k = 0; k < 16; ++k)
      ys[t][ri][k] = (vv[k] - mean) * rstd * ln2w[k] + ln2b[k];
  }
  __syncthreads();
  // complex linear 16->64 + LN3 over c (wave = 64 lanes = c) + PReLU
  int wv = tid >> 6, cc = tid & 63;
  float lr[16], li[16];
  #pragma unroll
  for (int q = 0; q < 4; ++q) {
    float4 v = *(const float4*)(lrw + cc * 16 + q * 4);
    lr[q*4+0] = v.x; lr[q*4+1] = v.y; lr[q*4+2] = v.z; lr[q*4+3] = v.w;
    float4 u = *(const float4*)(liw + cc * 16 + q * 4);
    li[q*4+0] = u.x; li[q*4+1] = u.y; li[q*4+2] = u.z; li[q*4+3] = u.w;
  }
  float brc = lrb[cc], bic = lib[cc];
  float w3 = ln3w[cc], b3 = ln3b[cc];
  float aP = pa[0];
  for (int tt = wv; tt < 40; tt += 4) {
    float zr = brc - bic, zi = brc + bic;
    #pragma unroll
    for (int k = 0; k < 16; ++k) {
      float yr = ys[tt][0][k], yi = ys[tt][1][k];
      zr += yr * lr[k] - yi * li[k];
      zi += yi * lr[k] + yr * li[k];
    }
    float s1 = zr, s2 = zr * zr, s3 = zi, s4 = zi * zi;
    #pragma unroll
    for (int m = 1; m < 64; m <<= 1) {
      s1 += __shfl_xor(s1, m, 64);
      s2 += __shfl_xor(s2, m, 64);
      s3 += __shfl_xor(s3, m, 64);
      s4 += __shfl_xor(s4, m, 64);
    }
    float mr = s1 * 0.015625f, vr = s2 * 0.015625f - mr * mr;
    float mi = s3 * 0.015625f, vi = s4 * 0.015625f - mi * mi;
    float r1 = (zr - mr) * rsqrtf(vr + 1e-5f) * w3 + b3;
    float r2 = (zi - mi) * rsqrtf(vi + 1e-5f) * w3 + b3;
    r1 = r1 >= 0.f ? r1 : aP * r1;
    r2 = r2 >= 0.f ? r2 : aP * r2;
    zs[cc][tt * 2 + 0] = r1;
    zs[cc][tt * 2 + 1] = r2;
  }
  __syncthreads();
  for (int i = 0; i < 5; ++i) {         // residual + coalesced write
    int idx = tid + i * 256;            // 64 c x 20 f4
    int c = idx / 20, q = idx - c * 20;
    size_t gaddr = (size_t)((n * 64 + c) * 100 + f) * 400 + t0 * 2 + q * 4;
    float4 v = *(const float4*)(in + gaddr);
    float4 z;
    z.x = zs[c][q*4+0] + v.x; z.y = zs[c][q*4+1] + v.y;
    z.z = zs[c][q*4+2] + v.z; z.w = zs[c][q*4+3] + v.w;
    *(float4*)(out + gaddr) = z;
  }
}

extern "C" void kernel_launch(void* const* d_in, const int* in_sizes, int n_in,
                              void* d_out, int out_size, void* d_ws, size_t ws_size,
                              hipStream_t stream) {
  (void)in_sizes; (void)n_in; (void)out_size;
  const float* inputs = (const float*)d_in[0];
  const float* Wih  = (const float*)d_in[1];
  const float* Whh  = (const float*)d_in[2];
  const float* bih  = (const float*)d_in[3];
  const float* bhh  = (const float*)d_in[4];
  const float* ln1w = (const float*)d_in[5];
  const float* ln1b = (const float*)d_in[6];
  const float* ln2w = (const float*)d_in[7];
  const float* ln2b = (const float*)d_in[8];
  const float* lrw  = (const float*)d_in[9];
  const float* lrb  = (const float*)d_in[10];
  const float* liw  = (const float*)d_in[11];
  const float* lib  = (const float*)d_in[12];
  const float* ln3w = (const float*)d_in[13];
  const float* ln3b = (const float*)d_in[14];
  const float* pa   = (const float*)d_in[15];
  float* out = (float*)d_out;
  char* ws = (char*)d_ws;

  // pick largest chunk NB (400,200,100,50,25) whose buffers fit ws_size
  int NB = 400;
  while (NB > 25 && 204800ull + (size_t)NB * 1075200ull > ws_size) NB /= 2;
  int nch = 400 / NB;

  float* bihh = (float*)(ws + 0);                        // 6 KB
  unsigned short* wbf = (unsigned short*)(ws + 8192);    // 192 KB bf16 Wih
  size_t o_xr = 204800;
  size_t o_xi = o_xr + (size_t)NB * 25600;
  size_t o_xg = o_xi + (size_t)NB * 25600;
  size_t o_h  = o_xg + (size_t)NB * 614400;
  size_t o_at = o_h  + (size_t)NB * 307200;
  unsigned short* xr = (unsigned short*)(ws + o_xr);
  unsigned short* xi = (unsigned short*)(ws + o_xi);
  unsigned short* xg = (unsigned short*)(ws + o_xg);
  float* hbuf = (float*)(ws + o_h);
  float* att  = (float*)(ws + o_at);

  k_prep<<<384, 256, 0, stream>>>(bih, bhh, Wih, bihh, wbf);
  int M = NB * 200;
  int nsb = (M + 63) >> 6;              // 64 m-rows per block (4 waves x 16)
  for (int ch = 0; ch < nch; ++ch) {
    int b0 = ch * NB;
    k_ln1 <<<NB * 4,   256, 0, stream>>>(inputs, ln1w, ln1b, xr, xi, b0);
    k_xg  <<<24 * nsb, 256, 0, stream>>>(xr, xi, wbf, bihh, xg, M, NB, nsb);
    k_lstm<<<NB * 6,    64, 0, stream>>>(xg, Whh, hbuf, NB);   // 1 wave = 4 chains
    k_attn<<<8 * NB,   256, 0, stream>>>(hbuf, att, NB);
    k_out <<<NB * 5,   256, 0, stream>>>(att, inputs, ln2w, ln2b, lrw, lrb,
                                         liw, lib, ln3w, ln3b, pa, out, b0, NB);
  }
}